// Round 1
// baseline (7444.126 us; speedup 1.0000x reference)
//
#include <hip/hip_runtime.h>
#include <hip/hip_bf16.h>
#include <hip/hip_cooperative_groups.h>

namespace cg = cooperative_groups;

typedef __attribute__((ext_vector_type(8))) short short8;
typedef __attribute__((ext_vector_type(4))) float floatx4;

#define NB 128
#define NP 196
#define NH 512
#define NV 32000
#define NT 19

__device__ __forceinline__ float bf2f(short s) {
  unsigned int u = ((unsigned int)(unsigned short)s) << 16;
  return __builtin_bit_cast(float, u);
}
__device__ __forceinline__ short f2bf(float f) {
  unsigned int u = __builtin_bit_cast(unsigned int, f);
  unsigned int lsb = (u >> 16) & 1u;
  u += 0x7fffu + lsb;
  return (short)(u >> 16);
}
__device__ __forceinline__ float sigf(float x) { return 1.f / (1.f + expf(-x)); }
// dual-mode scalar load: flag=1 -> bf16, flag=0 -> f32
__device__ __forceinline__ float ldw(int fl, const void* p, int i) {
  return fl ? bf2f(((const short*)p)[i]) : ((const float*)p)[i];
}

// ---------------- detect input dtype from features bit patterns ----------------
__global__ void k_detect(const unsigned int* __restrict__ w, int* __restrict__ flagp) {
  __shared__ int cnt;
  if (threadIdx.x == 0) cnt = 0;
  __syncthreads();
  int local = 0;
  for (int i = threadIdx.x; i < 4096; i += 256) {
    unsigned int lo = w[i] & 0xFFFFu;
    unsigned int ex = (lo >> 7) & 0xFFu;
    if (ex >= 110u && ex <= 135u) local++;
  }
  atomicAdd(&cnt, local);
  __syncthreads();
  if (threadIdx.x == 0) *flagp = (cnt > 2048) ? 1 : 0;
}

// ---------------- single merged convert kernel: 10 tensors -> contiguous bf16 ws ----------------
// dst layout order must match ws allocation: cfeat,cembed,cwfc,cwih,cwhh,cwenc,cwdec,cwbeta,cwinith,cwinitc
__global__ void k_convall(const void* __restrict__ s0, const void* __restrict__ s1,
                          const void* __restrict__ s2, const void* __restrict__ s3,
                          const void* __restrict__ s4, const void* __restrict__ s5,
                          const void* __restrict__ s6, const void* __restrict__ s7,
                          const void* __restrict__ s8, const void* __restrict__ s9,
                          short* __restrict__ dst, const int* __restrict__ flagp) {
  int fl = *flagp;
  const int totc = 50069504 / 8;  // total short8 chunks
  for (int c = blockIdx.x * 256 + threadIdx.x; c < totc; c += gridDim.x * 256) {
    int i = c * 8;
    const void* src;
    int off;
    if (i < 12845056)      { src = s0; off = i; }
    else if (i < 29229056) { src = s1; off = i - 12845056; }
    else if (i < 45613056) { src = s2; off = i - 29229056; }
    else if (i < 47710208) { src = s3; off = i - 45613056; }
    else if (i < 48758784) { src = s4; off = i - 47710208; }
    else if (i < 49020928) { src = s5; off = i - 48758784; }
    else if (i < 49283072) { src = s6; off = i - 49020928; }
    else if (i < 49545216) { src = s7; off = i - 49283072; }
    else if (i < 49807360) { src = s8; off = i - 49545216; }
    else                   { src = s9; off = i - 49807360; }
    if (fl) {
      ((short8*)dst)[c] = *(const short8*)((const short*)src + off);
    } else {
      const float* sp = (const float*)src + off;
      short8 o;
#pragma unroll
      for (int j = 0; j < 8; ++j) o[j] = f2bf(sp[j]);
      ((short8*)dst)[c] = o;
    }
  }
}

// ---------------- K0: fmean = mean_p features ----------------
__global__ void k_fmean(const short* __restrict__ feat, short* __restrict__ fmean) {
  int b = blockIdx.x;
  for (int e = threadIdx.x; e < NH; e += 256) {
    float s = 0.f;
    const short* fp = feat + (size_t)b * (NP * NH) + e;
    for (int p = 0; p < NP; ++p) s += bf2f(fp[p * NH]);
    fmean[b * NH + e] = f2bf(s * (1.f / 196.f));
  }
}

// ---------------- K1: h0/c0 init (M=128,N=1024,K=512) ----------------
__global__ void k_init(const short* __restrict__ fmean,
                       const short* __restrict__ w_init_h, const void* __restrict__ b_init_h,
                       const short* __restrict__ w_init_c, const void* __restrict__ b_init_c,
                       short* __restrict__ hbuf, float* __restrict__ cbuf,
                       const int* __restrict__ flagp) {
  int fl = *flagp;
  int wave = threadIdx.x >> 6, lane = threadIdx.x & 63;
  int rlo = lane & 15, quad = lane >> 4;
  int n = (blockIdx.x * 4 + wave) * 16 + rlo;
  const short* brow = (n < 512 ? w_init_h + (size_t)n * 512 : w_init_c + (size_t)(n - 512) * 512) + quad * 8;
  const short* arow = fmean + rlo * 512 + quad * 8;
  floatx4 acc[8];
#pragma unroll
  for (int mt = 0; mt < 8; ++mt) acc[mt] = (floatx4){0.f, 0.f, 0.f, 0.f};
  for (int k = 0; k < 512; k += 32) {
    short8 bfr = *(const short8*)(brow + k);
#pragma unroll
    for (int mt = 0; mt < 8; ++mt) {
      short8 afr = *(const short8*)(arow + mt * (16 * 512) + k);
      acc[mt] = __builtin_amdgcn_mfma_f32_16x16x32_bf16(afr, bfr, acc[mt], 0, 0, 0);
    }
  }
  float bias = (n < 512) ? ldw(fl, b_init_h, n) : ldw(fl, b_init_c, n - 512);
#pragma unroll
  for (int mt = 0; mt < 8; ++mt)
#pragma unroll
    for (int r = 0; r < 4; ++r) {
      int bb = mt * 16 + quad * 4 + r;
      float v = acc[mt][r] + bias;
      if (n < 512) hbuf[bb * 512 + n] = f2bf(v);
      else cbuf[bb * 512 + (n - 512)] = v;
    }
}

// ---------------- K2: att1 = features @ w_enc^T + b (M=25088,N=512,K=512) ----------------
__global__ void k_att1(const short* __restrict__ feat, const short* __restrict__ w_enc,
                       const void* __restrict__ b_enc, short* __restrict__ att1,
                       const int* __restrict__ flagp) {
  int fl = *flagp;
  int wave = threadIdx.x >> 6, lane = threadIdx.x & 63;
  int rlo = lane & 15, quad = lane >> 4;
  int n = (blockIdx.x * 4 + wave) * 16 + rlo;
  int mbase = blockIdx.y * 128;
  const short* brow = w_enc + (size_t)n * 512 + quad * 8;
  const short* arow = feat + (size_t)(mbase + rlo) * 512 + quad * 8;
  floatx4 acc[8];
#pragma unroll
  for (int mt = 0; mt < 8; ++mt) acc[mt] = (floatx4){0.f, 0.f, 0.f, 0.f};
  for (int k = 0; k < 512; k += 32) {
    short8 bfr = *(const short8*)(brow + k);
#pragma unroll
    for (int mt = 0; mt < 8; ++mt) {
      short8 afr = *(const short8*)(arow + (size_t)mt * (16 * 512) + k);
      acc[mt] = __builtin_amdgcn_mfma_f32_16x16x32_bf16(afr, bfr, acc[mt], 0, 0, 0);
    }
  }
  float bias = ldw(fl, b_enc, n);
#pragma unroll
  for (int mt = 0; mt < 8; ++mt)
#pragma unroll
    for (int r = 0; r < 4; ++r) {
      int m = mbase + mt * 16 + quad * 4 + r;
      att1[(size_t)m * 512 + n] = f2bf(acc[mt][r] + bias);
    }
}

// ---------------- K3: xpart[t,b,:] = emb @ w_ih[:, :512]^T + b_ih + b_hh ----------------
__global__ void k_xpart(const int* __restrict__ captions, const short* __restrict__ embed_w,
                        const short* __restrict__ w_ih, const void* __restrict__ b_ih,
                        const void* __restrict__ b_hh, float* __restrict__ xp,
                        const int* __restrict__ flagp) {
  int fl = *flagp;
  int wave = threadIdx.x >> 6, lane = threadIdx.x & 63;
  int rlo = lane & 15, quad = lane >> 4;
  int t = blockIdx.y;
  int n = (blockIdx.x * 4 + wave) * 16 + rlo;
  const short* brow = w_ih + (size_t)n * 1024 + quad * 8;
  int tok[8];
#pragma unroll
  for (int mt = 0; mt < 8; ++mt) tok[mt] = captions[(mt * 16 + rlo) * 20 + t];
  floatx4 acc[8];
#pragma unroll
  for (int mt = 0; mt < 8; ++mt) acc[mt] = (floatx4){0.f, 0.f, 0.f, 0.f};
  for (int k = 0; k < 512; k += 32) {
    short8 bfr = *(const short8*)(brow + k);
#pragma unroll
    for (int mt = 0; mt < 8; ++mt) {
      short8 afr = *(const short8*)(embed_w + (size_t)tok[mt] * 512 + quad * 8 + k);
      acc[mt] = __builtin_amdgcn_mfma_f32_16x16x32_bf16(afr, bfr, acc[mt], 0, 0, 0);
    }
  }
  float bias = ldw(fl, b_ih, n) + ldw(fl, b_hh, n);
#pragma unroll
  for (int mt = 0; mt < 8; ++mt)
#pragma unroll
    for (int r = 0; r < 4; ++r) {
      int bb = mt * 16 + quad * 4 + r;
      xp[((size_t)t * 128 + bb) * 2048 + n] = acc[mt][r] + bias;
    }
}

// ---------------- cooperative fused decode loop: hproj -> attn -> gates+LSTM, 19 steps ----------------
__global__ void k_loop(short* __restrict__ hbuf,
                       const short* __restrict__ w_dec, const void* __restrict__ b_dec,
                       const short* __restrict__ w_beta, const void* __restrict__ b_beta,
                       const short* __restrict__ w_hh, float* __restrict__ abuf,
                       const int* __restrict__ flagp,
                       const short* __restrict__ att1, const short* __restrict__ feat,
                       const void* __restrict__ w_full, const int* __restrict__ lengths,
                       short* __restrict__ awe, void* __restrict__ d_out,
                       const short* __restrict__ w_ih, const float* __restrict__ xp,
                       float* __restrict__ cbuf, short* __restrict__ hnall) {
  cg::grid_group gg = cg::this_grid();
  int fl = *flagp;
  int blk = blockIdx.x;
  int tid = threadIdx.x, wave = tid >> 6, lane = tid & 63;
  int rlo = lane & 15, quad = lane >> 4;
  __shared__ float sm[196];
  __shared__ float gsm[4][128][17];  // +1 pad: kill bank conflicts

  float wfr[8];  // w_full is loop-invariant
#pragma unroll
  for (int j = 0; j < 8; ++j) wfr[j] = ldw(fl, w_full, lane + j * 64);

  for (int t = 0; t < NT; ++t) {
    // ---- phase 1: abuf = h @ [w_dec|w_beta|w_hh]^T (+biases)  (blocks 0..47)
    if (blk < 48) {
      int n = (blk * 4 + wave) * 16 + rlo;  // 0..3071
      const short* brow;
      float bias;
      if (n < 512)       { brow = w_dec  + (size_t)n * 512;          bias = ldw(fl, b_dec, n); }
      else if (n < 1024) { brow = w_beta + (size_t)(n - 512) * 512;  bias = ldw(fl, b_beta, n - 512); }
      else               { brow = w_hh   + (size_t)(n - 1024) * 512; bias = 0.f; }
      brow += quad * 8;
      const short* arow = hbuf + rlo * 512 + quad * 8;
      floatx4 acc[8];
#pragma unroll
      for (int mt = 0; mt < 8; ++mt) acc[mt] = (floatx4){0.f, 0.f, 0.f, 0.f};
      for (int k = 0; k < 512; k += 32) {
        short8 bfr = *(const short8*)(brow + k);
#pragma unroll
        for (int mt = 0; mt < 8; ++mt) {
          short8 afr = *(const short8*)(arow + mt * (16 * 512) + k);
          acc[mt] = __builtin_amdgcn_mfma_f32_16x16x32_bf16(afr, bfr, acc[mt], 0, 0, 0);
        }
      }
#pragma unroll
      for (int mt = 0; mt < 8; ++mt)
#pragma unroll
        for (int r = 0; r < 4; ++r) {
          int bb = mt * 16 + quad * 4 + r;
          abuf[(size_t)bb * 3072 + n] = acc[mt][r] + bias;
        }
    }
    gg.sync();

    // ---- phase 2: attention scores + softmax + context (all 128 blocks, one b each)
    {
      int b = blk;
      float att2r[8];
#pragma unroll
      for (int j = 0; j < 8; ++j) att2r[j] = abuf[(size_t)b * 3072 + lane + j * 64];
      for (int p = wave; p < NP; p += 4) {
        const short* arow = att1 + ((size_t)b * NP + p) * 512;
        float s = 0.f;
#pragma unroll
        for (int j = 0; j < 8; ++j) {
          float v = bf2f(arow[lane + j * 64]) + att2r[j];
          s += fmaxf(v, 0.f) * wfr[j];
        }
#pragma unroll
        for (int off = 32; off >= 1; off >>= 1) s += __shfl_xor(s, off, 64);
        if (lane == 0) sm[p] = s;
      }
      __syncthreads();
      bool act = t < (lengths[b] - 1);
      if (wave == 0) {
        float v0 = sm[lane], v1 = sm[lane + 64], v2 = sm[lane + 128];
        float v3 = (lane < 4) ? sm[lane + 192] : -1e30f;
        float m = fmaxf(fmaxf(v0, v1), fmaxf(v2, v3));
#pragma unroll
        for (int off = 32; off >= 1; off >>= 1) m = fmaxf(m, __shfl_xor(m, off, 64));
        float e0 = expf(v0 - m), e1 = expf(v1 - m), e2 = expf(v2 - m);
        float e3 = (lane < 4) ? expf(v3 - m) : 0.f;
        float s = e0 + e1 + e2 + e3;
#pragma unroll
        for (int off = 32; off >= 1; off >>= 1) s += __shfl_xor(s, off, 64);
        float inv = 1.f / s;
        float a0 = e0 * inv, a1 = e1 * inv, a2 = e2 * inv, a3 = e3 * inv;
        sm[lane] = a0; sm[lane + 64] = a1; sm[lane + 128] = a2;
        if (lane < 4) sm[lane + 192] = a3;
        size_t ob = (size_t)NB * NT * NV + ((size_t)b * NT + t) * NP;
        float o0 = act ? a0 : 0.f, o1 = act ? a1 : 0.f, o2 = act ? a2 : 0.f, o3 = act ? a3 : 0.f;
        if (fl) {
          short* op = (short*)d_out;
          op[ob + lane] = f2bf(o0); op[ob + lane + 64] = f2bf(o1); op[ob + lane + 128] = f2bf(o2);
          if (lane < 4) op[ob + lane + 192] = f2bf(o3);
        } else {
          float* op = (float*)d_out;
          op[ob + lane] = o0; op[ob + lane + 64] = o1; op[ob + lane + 128] = o2;
          if (lane < 4) op[ob + lane + 192] = o3;
        }
      }
      __syncthreads();
      for (int e = tid; e < NH; e += 256) {
        float s = 0.f;
        const short* fp = feat + (size_t)b * NP * NH + e;
        for (int p = 0; p < NP; ++p) s += sm[p] * bf2f(fp[p * NH]);
        float gate = sigf(abuf[(size_t)b * 3072 + 512 + e]);
        awe[b * NH + e] = f2bf(gate * s);
      }
    }
    gg.sync();

    // ---- phase 3: gates GEMM + LSTM pointwise (blocks 0..31)
    if (blk < 32) {
      int n = wave * 512 + blk * 16 + rlo;  // gate g=wave, 16-col slice
      const short* brow = w_ih + (size_t)n * 1024 + 512 + quad * 8;
      const short* arow = awe + rlo * 512 + quad * 8;
      floatx4 acc[8];
#pragma unroll
      for (int mt = 0; mt < 8; ++mt) acc[mt] = (floatx4){0.f, 0.f, 0.f, 0.f};
      for (int k = 0; k < 512; k += 32) {
        short8 bfr = *(const short8*)(brow + k);
#pragma unroll
        for (int mt = 0; mt < 8; ++mt) {
          short8 afr = *(const short8*)(arow + mt * (16 * 512) + k);
          acc[mt] = __builtin_amdgcn_mfma_f32_16x16x32_bf16(afr, bfr, acc[mt], 0, 0, 0);
        }
      }
#pragma unroll
      for (int mt = 0; mt < 8; ++mt)
#pragma unroll
        for (int r = 0; r < 4; ++r) {
          int bb = mt * 16 + quad * 4 + r;
          float v = acc[mt][r] + xp[((size_t)t * 128 + bb) * 2048 + n] + abuf[(size_t)bb * 3072 + 1024 + n];
          gsm[wave][bb][rlo] = v;
        }
      __syncthreads();
      for (int idx = tid; idx < 2048; idx += 256) {
        int bb = idx >> 4, jl = idx & 15;
        int j = blk * 16 + jl;
        float ig = gsm[0][bb][jl], fg = gsm[1][bb][jl], ggt = gsm[2][bb][jl], og = gsm[3][bb][jl];
        float co = cbuf[bb * 512 + j];
        float cn = sigf(fg) * co + sigf(ig) * tanhf(ggt);
        float hn = sigf(og) * tanhf(cn);
        hnall[(size_t)t * (128 * 512) + bb * 512 + j] = f2bf(hn);
        if (t < lengths[bb] - 1) {
          cbuf[bb * 512 + j] = cn;
          hbuf[bb * 512 + j] = f2bf(hn);
        }
      }
    }
    gg.sync();
  }
}

// ---------------- batched preds: [2432 x 32000 x 512] GEMM, w_fc read once ----------------
// grid 250: block tile 128m(all bb) x 128n, LDS-chunked K (4 x 128), 2x2 waves of 64x64
__global__ void k_preds_all(const short* __restrict__ hnall, const short* __restrict__ w_fc,
                            const void* __restrict__ b_fc, const int* __restrict__ lengths,
                            void* __restrict__ d_out, const int* __restrict__ flagp) {
  int fl = *flagp;
  int tid = threadIdx.x, wave = tid >> 6, lane = tid & 63;
  int rlo = lane & 15, quad = lane >> 4;
  int n0 = blockIdx.x * 128;
  int mh = (wave >> 1) * 64;  // wave's m-half: 0 or 64
  int nh = (wave & 1) * 64;   // wave's n-half: 0 or 64
  __shared__ short Al[128 * 128];  // 32 KB, XOR-swizzled rows
  __shared__ short Bl[128 * 128];  // 32 KB, XOR-swizzled rows

  float bias[4];
#pragma unroll
  for (int nf = 0; nf < 4; ++nf) bias[nf] = ldw(fl, b_fc, n0 + nh + nf * 16 + rlo);

  for (int t = 0; t < NT; ++t) {
    floatx4 acc[4][4];
#pragma unroll
    for (int mt = 0; mt < 4; ++mt)
#pragma unroll
      for (int nf = 0; nf < 4; ++nf) acc[mt][nf] = (floatx4){0.f, 0.f, 0.f, 0.f};

    for (int kc = 0; kc < 4; ++kc) {
      // stage A (hn rows 0..127) and B (w_fc rows n0..n0+127), k in [kc*128, kc*128+128)
#pragma unroll
      for (int j = 0; j < 8; ++j) {
        int idx = j * 256 + tid;  // 0..2047
        int row = idx >> 4, c8 = idx & 15;
        int sw = (c8 * 16) ^ ((row & 7) << 4);  // swizzled byte offset within row
        short8 va = *(const short8*)(hnall + ((size_t)t * 128 + row) * 512 + kc * 128 + c8 * 8);
        *(short8*)((char*)Al + row * 256 + sw) = va;
        short8 vb = *(const short8*)(w_fc + (size_t)(n0 + row) * 512 + kc * 128 + c8 * 8);
        *(short8*)((char*)Bl + row * 256 + sw) = vb;
      }
      __syncthreads();
#pragma unroll
      for (int kkl = 0; kkl < 4; ++kkl) {
        int kb = kkl * 64 + quad * 16;  // byte offset of this lane's k-slice
        short8 afr[4], bfr[4];
#pragma unroll
        for (int mt = 0; mt < 4; ++mt) {
          int row = mh + mt * 16 + rlo;
          afr[mt] = *(const short8*)((const char*)Al + row * 256 + (kb ^ ((row & 7) << 4)));
        }
#pragma unroll
        for (int nf = 0; nf < 4; ++nf) {
          int row = nh + nf * 16 + rlo;
          bfr[nf] = *(const short8*)((const char*)Bl + row * 256 + (kb ^ ((row & 7) << 4)));
        }
#pragma unroll
        for (int mt = 0; mt < 4; ++mt)
#pragma unroll
          for (int nf = 0; nf < 4; ++nf)
            acc[mt][nf] = __builtin_amdgcn_mfma_f32_16x16x32_bf16(afr[mt], bfr[nf], acc[mt][nf], 0, 0, 0);
      }
      __syncthreads();
    }
    // epilogue: bias + mask + store
#pragma unroll
    for (int mt = 0; mt < 4; ++mt)
#pragma unroll
      for (int r = 0; r < 4; ++r) {
        int bb = mh + mt * 16 + quad * 4 + r;
        bool act = t < lengths[bb] - 1;
#pragma unroll
        for (int nf = 0; nf < 4; ++nf) {
          int n = n0 + nh + nf * 16 + rlo;
          float v = act ? (acc[mt][nf][r] + bias[nf]) : 0.f;
          size_t oi = ((size_t)bb * NT + t) * NV + n;
          if (fl) ((short*)d_out)[oi] = f2bf(v);
          else ((float*)d_out)[oi] = v;
        }
      }
  }
}

extern "C" void kernel_launch(void* const* d_in, const int* in_sizes, int n_in,
                              void* d_out, int out_size, void* d_ws, size_t ws_size,
                              hipStream_t stream) {
  const void* features = d_in[0];
  const int* captions = (const int*)d_in[1];
  const int* lengths = (const int*)d_in[2];
  const void* w_enc_att = d_in[3];
  const void* b_enc_att = d_in[4];
  const void* w_dec_att = d_in[5];
  const void* b_dec_att = d_in[6];
  const void* w_full = d_in[7];
  const void* embed_w = d_in[9];
  const void* w_ih = d_in[10];
  const void* b_ih = d_in[11];
  const void* w_hh = d_in[12];
  const void* b_hh = d_in[13];
  const void* w_init_h = d_in[14];
  const void* b_init_h = d_in[15];
  const void* w_init_c = d_in[16];
  const void* b_init_c = d_in[17];
  const void* w_beta = d_in[18];
  const void* b_beta = d_in[19];
  const void* w_fc = d_in[20];
  const void* b_fc = d_in[21];

  char* ws = (char*)d_ws;
  int* flagp = (int*)ws; ws += 16;
  short* cfeat = (short*)ws; ws += (size_t)12845056 * 2;
  short* cembed = (short*)ws; ws += (size_t)16384000 * 2;
  short* cwfc = (short*)ws; ws += (size_t)16384000 * 2;
  short* cwih = (short*)ws; ws += (size_t)2097152 * 2;
  short* cwhh = (short*)ws; ws += (size_t)1048576 * 2;
  short* cwenc = (short*)ws; ws += (size_t)262144 * 2;
  short* cwdec = (short*)ws; ws += (size_t)262144 * 2;
  short* cwbeta = (short*)ws; ws += (size_t)262144 * 2;
  short* cwinith = (short*)ws; ws += (size_t)262144 * 2;
  short* cwinitc = (short*)ws; ws += (size_t)262144 * 2;
  short* att1 = (short*)ws; ws += (size_t)25088 * 512 * 2;
  float* xp   = (float*)ws; ws += (size_t)2432 * 2048 * 4;
  float* abuf = (float*)ws; ws += (size_t)128 * 3072 * 4;
  short* hbuf = (short*)ws; ws += 128 * 512 * 2;
  short* hnall = (short*)ws; ws += (size_t)NT * 128 * 512 * 2;
  short* awe  = (short*)ws; ws += 128 * 512 * 2;
  short* fmean = (short*)ws; ws += 128 * 512 * 2;
  float* cbuf = (float*)ws; ws += 128 * 512 * 4;

  k_detect<<<1, 256, 0, stream>>>((const unsigned int*)features, flagp);
  k_convall<<<2048, 256, 0, stream>>>(features, embed_w, w_fc, w_ih, w_hh,
                                      w_enc_att, w_dec_att, w_beta, w_init_h, w_init_c,
                                      cfeat, flagp);

  k_fmean<<<128, 256, 0, stream>>>(cfeat, fmean);
  k_att1<<<dim3(8, 196), 256, 0, stream>>>(cfeat, cwenc, b_enc_att, att1, flagp);
  k_xpart<<<dim3(32, NT), 256, 0, stream>>>(captions, cembed, cwih, b_ih, b_hh, xp, flagp);
  k_init<<<16, 256, 0, stream>>>(fmean, cwinith, b_init_h, cwinitc, b_init_c, hbuf, cbuf, flagp);

  void* kargs[] = {(void*)&hbuf, (void*)&cwdec, (void*)&b_dec_att, (void*)&cwbeta, (void*)&b_beta,
                   (void*)&cwhh, (void*)&abuf, (void*)&flagp, (void*)&att1, (void*)&cfeat,
                   (void*)&w_full, (void*)&lengths, (void*)&awe, (void*)&d_out, (void*)&cwih,
                   (void*)&xp, (void*)&cbuf, (void*)&hnall};
  hipLaunchCooperativeKernel(k_loop, dim3(128), dim3(256), kargs, 0, stream);

  k_preds_all<<<250, 256, 0, stream>>>(hnall, cwfc, b_fc, lengths, d_out, flagp);
}

// Round 2
// 2689.077 us; speedup vs baseline: 2.7683x; 2.7683x over previous
//
#include <hip/hip_runtime.h>
#include <hip/hip_bf16.h>

typedef __attribute__((ext_vector_type(8))) short short8;
typedef __attribute__((ext_vector_type(4))) float floatx4;

#define NB 128
#define NP 196
#define NH 512
#define NV 32000
#define NT 19

__device__ __forceinline__ float bf2f(short s) {
  unsigned int u = ((unsigned int)(unsigned short)s) << 16;
  return __builtin_bit_cast(float, u);
}
__device__ __forceinline__ short f2bf(float f) {
  unsigned int u = __builtin_bit_cast(unsigned int, f);
  unsigned int lsb = (u >> 16) & 1u;
  u += 0x7fffu + lsb;
  return (short)(u >> 16);
}
__device__ __forceinline__ float sigf(float x) { return 1.f / (1.f + expf(-x)); }
// dual-mode scalar load: flag=1 -> bf16, flag=0 -> f32
__device__ __forceinline__ float ldw(int fl, const void* p, int i) {
  return fl ? bf2f(((const short*)p)[i]) : ((const float*)p)[i];
}

// ---------------- detect input dtype from features bit patterns ----------------
__global__ void k_detect(const unsigned int* __restrict__ w, int* __restrict__ flagp) {
  __shared__ int cnt;
  if (threadIdx.x == 0) cnt = 0;
  __syncthreads();
  int local = 0;
  for (int i = threadIdx.x; i < 4096; i += 256) {
    unsigned int lo = w[i] & 0xFFFFu;
    unsigned int ex = (lo >> 7) & 0xFFu;
    if (ex >= 110u && ex <= 135u) local++;
  }
  atomicAdd(&cnt, local);
  __syncthreads();
  if (threadIdx.x == 0) *flagp = (cnt > 2048) ? 1 : 0;
}

// ---------------- single merged convert kernel: 10 tensors -> contiguous bf16 ws ----------------
__global__ void k_convall(const void* __restrict__ s0, const void* __restrict__ s1,
                          const void* __restrict__ s2, const void* __restrict__ s3,
                          const void* __restrict__ s4, const void* __restrict__ s5,
                          const void* __restrict__ s6, const void* __restrict__ s7,
                          const void* __restrict__ s8, const void* __restrict__ s9,
                          short* __restrict__ dst, const int* __restrict__ flagp) {
  int fl = *flagp;
  const int totc = 50069504 / 8;  // total short8 chunks
  for (int c = blockIdx.x * 256 + threadIdx.x; c < totc; c += gridDim.x * 256) {
    int i = c * 8;
    const void* src;
    int off;
    if (i < 12845056)      { src = s0; off = i; }
    else if (i < 29229056) { src = s1; off = i - 12845056; }
    else if (i < 45613056) { src = s2; off = i - 29229056; }
    else if (i < 47710208) { src = s3; off = i - 45613056; }
    else if (i < 48758784) { src = s4; off = i - 47710208; }
    else if (i < 49020928) { src = s5; off = i - 48758784; }
    else if (i < 49283072) { src = s6; off = i - 49020928; }
    else if (i < 49545216) { src = s7; off = i - 49283072; }
    else if (i < 49807360) { src = s8; off = i - 49545216; }
    else                   { src = s9; off = i - 49807360; }
    if (fl) {
      ((short8*)dst)[c] = *(const short8*)((const short*)src + off);
    } else {
      const float* sp = (const float*)src + off;
      short8 o;
#pragma unroll
      for (int j = 0; j < 8; ++j) o[j] = f2bf(sp[j]);
      ((short8*)dst)[c] = o;
    }
  }
}

// ---------------- K0: fmean = mean_p features ----------------
__global__ void k_fmean(const short* __restrict__ feat, short* __restrict__ fmean) {
  int b = blockIdx.x;
  for (int e = threadIdx.x; e < NH; e += 256) {
    float s = 0.f;
    const short* fp = feat + (size_t)b * (NP * NH) + e;
    for (int p = 0; p < NP; ++p) s += bf2f(fp[p * NH]);
    fmean[b * NH + e] = f2bf(s * (1.f / 196.f));
  }
}

// ---------------- K1: h0/c0 init (M=128,N=1024,K=512) ----------------
__global__ void k_init(const short* __restrict__ fmean,
                       const short* __restrict__ w_init_h, const void* __restrict__ b_init_h,
                       const short* __restrict__ w_init_c, const void* __restrict__ b_init_c,
                       short* __restrict__ hbuf, float* __restrict__ cbuf,
                       const int* __restrict__ flagp) {
  int fl = *flagp;
  int wave = threadIdx.x >> 6, lane = threadIdx.x & 63;
  int rlo = lane & 15, quad = lane >> 4;
  int n = (blockIdx.x * 4 + wave) * 16 + rlo;
  const short* brow = (n < 512 ? w_init_h + (size_t)n * 512 : w_init_c + (size_t)(n - 512) * 512) + quad * 8;
  const short* arow = fmean + rlo * 512 + quad * 8;
  floatx4 acc[8];
#pragma unroll
  for (int mt = 0; mt < 8; ++mt) acc[mt] = (floatx4){0.f, 0.f, 0.f, 0.f};
  for (int k = 0; k < 512; k += 32) {
    short8 bfr = *(const short8*)(brow + k);
#pragma unroll
    for (int mt = 0; mt < 8; ++mt) {
      short8 afr = *(const short8*)(arow + mt * (16 * 512) + k);
      acc[mt] = __builtin_amdgcn_mfma_f32_16x16x32_bf16(afr, bfr, acc[mt], 0, 0, 0);
    }
  }
  float bias = (n < 512) ? ldw(fl, b_init_h, n) : ldw(fl, b_init_c, n - 512);
#pragma unroll
  for (int mt = 0; mt < 8; ++mt)
#pragma unroll
    for (int r = 0; r < 4; ++r) {
      int bb = mt * 16 + quad * 4 + r;
      float v = acc[mt][r] + bias;
      if (n < 512) hbuf[bb * 512 + n] = f2bf(v);
      else cbuf[bb * 512 + (n - 512)] = v;
    }
}

// ---------------- K2: att1 = features @ w_enc^T + b (M=25088,N=512,K=512) ----------------
__global__ void k_att1(const short* __restrict__ feat, const short* __restrict__ w_enc,
                       const void* __restrict__ b_enc, short* __restrict__ att1,
                       const int* __restrict__ flagp) {
  int fl = *flagp;
  int wave = threadIdx.x >> 6, lane = threadIdx.x & 63;
  int rlo = lane & 15, quad = lane >> 4;
  int n = (blockIdx.x * 4 + wave) * 16 + rlo;
  int mbase = blockIdx.y * 128;
  const short* brow = w_enc + (size_t)n * 512 + quad * 8;
  const short* arow = feat + (size_t)(mbase + rlo) * 512 + quad * 8;
  floatx4 acc[8];
#pragma unroll
  for (int mt = 0; mt < 8; ++mt) acc[mt] = (floatx4){0.f, 0.f, 0.f, 0.f};
  for (int k = 0; k < 512; k += 32) {
    short8 bfr = *(const short8*)(brow + k);
#pragma unroll
    for (int mt = 0; mt < 8; ++mt) {
      short8 afr = *(const short8*)(arow + (size_t)mt * (16 * 512) + k);
      acc[mt] = __builtin_amdgcn_mfma_f32_16x16x32_bf16(afr, bfr, acc[mt], 0, 0, 0);
    }
  }
  float bias = ldw(fl, b_enc, n);
#pragma unroll
  for (int mt = 0; mt < 8; ++mt)
#pragma unroll
    for (int r = 0; r < 4; ++r) {
      int m = mbase + mt * 16 + quad * 4 + r;
      att1[(size_t)m * 512 + n] = f2bf(acc[mt][r] + bias);
    }
}

// ---------------- K3: xpart[t,b,:] = emb @ w_ih[:, :512]^T + b_ih + b_hh ----------------
__global__ void k_xpart(const int* __restrict__ captions, const short* __restrict__ embed_w,
                        const short* __restrict__ w_ih, const void* __restrict__ b_ih,
                        const void* __restrict__ b_hh, float* __restrict__ xp,
                        const int* __restrict__ flagp) {
  int fl = *flagp;
  int wave = threadIdx.x >> 6, lane = threadIdx.x & 63;
  int rlo = lane & 15, quad = lane >> 4;
  int t = blockIdx.y;
  int n = (blockIdx.x * 4 + wave) * 16 + rlo;
  const short* brow = w_ih + (size_t)n * 1024 + quad * 8;
  int tok[8];
#pragma unroll
  for (int mt = 0; mt < 8; ++mt) tok[mt] = captions[(mt * 16 + rlo) * 20 + t];
  floatx4 acc[8];
#pragma unroll
  for (int mt = 0; mt < 8; ++mt) acc[mt] = (floatx4){0.f, 0.f, 0.f, 0.f};
  for (int k = 0; k < 512; k += 32) {
    short8 bfr = *(const short8*)(brow + k);
#pragma unroll
    for (int mt = 0; mt < 8; ++mt) {
      short8 afr = *(const short8*)(embed_w + (size_t)tok[mt] * 512 + quad * 8 + k);
      acc[mt] = __builtin_amdgcn_mfma_f32_16x16x32_bf16(afr, bfr, acc[mt], 0, 0, 0);
    }
  }
  float bias = ldw(fl, b_ih, n) + ldw(fl, b_hh, n);
#pragma unroll
  for (int mt = 0; mt < 8; ++mt)
#pragma unroll
    for (int r = 0; r < 4; ++r) {
      int bb = mt * 16 + quad * 4 + r;
      xp[((size_t)t * 128 + bb) * 2048 + n] = acc[mt][r] + bias;
    }
}

// ---------------- KA: abuf = h @ [w_dec|w_beta|w_hh]^T (+biases) ----------------
__global__ void k_hproj(const short* __restrict__ hbuf,
                        const short* __restrict__ w_dec, const void* __restrict__ b_dec,
                        const short* __restrict__ w_beta, const void* __restrict__ b_beta,
                        const short* __restrict__ w_hh, float* __restrict__ abuf,
                        const int* __restrict__ flagp) {
  int fl = *flagp;
  int wave = threadIdx.x >> 6, lane = threadIdx.x & 63;
  int rlo = lane & 15, quad = lane >> 4;
  int n = (blockIdx.x * 4 + wave) * 16 + rlo;  // 0..3071
  const short* brow;
  float bias;
  if (n < 512)       { brow = w_dec  + (size_t)n * 512;          bias = ldw(fl, b_dec, n); }
  else if (n < 1024) { brow = w_beta + (size_t)(n - 512) * 512;  bias = ldw(fl, b_beta, n - 512); }
  else               { brow = w_hh   + (size_t)(n - 1024) * 512; bias = 0.f; }
  brow += quad * 8;
  const short* arow = hbuf + rlo * 512 + quad * 8;
  floatx4 acc[8];
#pragma unroll
  for (int mt = 0; mt < 8; ++mt) acc[mt] = (floatx4){0.f, 0.f, 0.f, 0.f};
  for (int k = 0; k < 512; k += 32) {
    short8 bfr = *(const short8*)(brow + k);
#pragma unroll
    for (int mt = 0; mt < 8; ++mt) {
      short8 afr = *(const short8*)(arow + mt * (16 * 512) + k);
      acc[mt] = __builtin_amdgcn_mfma_f32_16x16x32_bf16(afr, bfr, acc[mt], 0, 0, 0);
    }
  }
#pragma unroll
  for (int mt = 0; mt < 8; ++mt)
#pragma unroll
    for (int r = 0; r < 4; ++r) {
      int bb = mt * 16 + quad * 4 + r;
      abuf[(size_t)bb * 3072 + n] = acc[mt][r] + bias;
    }
}

// ---------------- KB1: scores e[b,p] for all 25088 rows, full-GPU grid ----------------
// one wave per 8 rows; row read as one short8 per lane (1KB per wave-load)
__global__ void k_score(const short* __restrict__ att1, const float* __restrict__ abuf,
                        const void* __restrict__ w_full, float* __restrict__ escore,
                        const int* __restrict__ flagp) {
  int fl = *flagp;
  int wave = threadIdx.x >> 6, lane = threadIdx.x & 63;
  int gw = blockIdx.x * 4 + wave;  // 0..3135
  int r0 = gw * 8;
  float wfr[8];
#pragma unroll
  for (int j = 0; j < 8; ++j) wfr[j] = ldw(fl, w_full, lane * 8 + j);
#pragma unroll
  for (int rr = 0; rr < 8; ++rr) {
    int r = r0 + rr;      // 0..25087
    int b = r / 196;
    const float* a2 = abuf + (size_t)b * 3072 + lane * 8;
    floatx4 a2a = *(const floatx4*)a2;
    floatx4 a2b = *(const floatx4*)(a2 + 4);
    short8 v = *(const short8*)(att1 + (size_t)r * 512 + lane * 8);
    float s = 0.f;
    s += fmaxf(bf2f(v[0]) + a2a[0], 0.f) * wfr[0];
    s += fmaxf(bf2f(v[1]) + a2a[1], 0.f) * wfr[1];
    s += fmaxf(bf2f(v[2]) + a2a[2], 0.f) * wfr[2];
    s += fmaxf(bf2f(v[3]) + a2a[3], 0.f) * wfr[3];
    s += fmaxf(bf2f(v[4]) + a2b[0], 0.f) * wfr[4];
    s += fmaxf(bf2f(v[5]) + a2b[1], 0.f) * wfr[5];
    s += fmaxf(bf2f(v[6]) + a2b[2], 0.f) * wfr[6];
    s += fmaxf(bf2f(v[7]) + a2b[3], 0.f) * wfr[7];
#pragma unroll
    for (int off = 32; off >= 1; off >>= 1) s += __shfl_xor(s, off, 64);
    if (lane == 0) escore[r] = s;
  }
}

// ---------------- KB2: softmax (redundant per block) + context chunk + gate ----------------
// grid (4 e-chunks, 128 b); block (ec,b) computes awe[b, ec*128 : ec*128+128)
__global__ void k_ctx(const float* __restrict__ escore, const short* __restrict__ feat,
                      const float* __restrict__ abuf, const int* __restrict__ lengths,
                      short* __restrict__ awe, void* __restrict__ d_out,
                      const int* __restrict__ flagp, int t) {
  int fl = *flagp;
  int ec = blockIdx.x;  // 0..3
  int b = blockIdx.y;   // 0..127
  int tid = threadIdx.x, wave = tid >> 6, lane = tid & 63;
  __shared__ float sm[196];
  __shared__ float psum[4][128];
  for (int p = tid; p < NP; p += 256) sm[p] = escore[b * NP + p];
  __syncthreads();
  bool act = t < (lengths[b] - 1);
  if (wave == 0) {
    float v0 = sm[lane], v1 = sm[lane + 64], v2 = sm[lane + 128];
    float v3 = (lane < 4) ? sm[lane + 192] : -1e30f;
    float m = fmaxf(fmaxf(v0, v1), fmaxf(v2, v3));
#pragma unroll
    for (int off = 32; off >= 1; off >>= 1) m = fmaxf(m, __shfl_xor(m, off, 64));
    float e0 = expf(v0 - m), e1 = expf(v1 - m), e2 = expf(v2 - m);
    float e3 = (lane < 4) ? expf(v3 - m) : 0.f;
    float s = e0 + e1 + e2 + e3;
#pragma unroll
    for (int off = 32; off >= 1; off >>= 1) s += __shfl_xor(s, off, 64);
    float inv = 1.f / s;
    float a0 = e0 * inv, a1 = e1 * inv, a2 = e2 * inv, a3 = e3 * inv;
    sm[lane] = a0; sm[lane + 64] = a1; sm[lane + 128] = a2;
    if (lane < 4) sm[lane + 192] = a3;
    if (ec == 0) {
      size_t ob = (size_t)NB * NT * NV + ((size_t)b * NT + t) * NP;
      float o0 = act ? a0 : 0.f, o1 = act ? a1 : 0.f, o2 = act ? a2 : 0.f, o3 = act ? a3 : 0.f;
      if (fl) {
        short* op = (short*)d_out;
        op[ob + lane] = f2bf(o0); op[ob + lane + 64] = f2bf(o1); op[ob + lane + 128] = f2bf(o2);
        if (lane < 4) op[ob + lane + 192] = f2bf(o3);
      } else {
        float* op = (float*)d_out;
        op[ob + lane] = o0; op[ob + lane + 64] = o1; op[ob + lane + 128] = o2;
        if (lane < 4) op[ob + lane + 192] = o3;
      }
    }
  }
  __syncthreads();
  // context: wave w reduces p = w, w+4, ...; lane covers 2 consecutive e's
  int eoff = ec * 128 + lane * 2;
  const short* fb = feat + (size_t)b * (NP * NH) + eoff;
  float acc0 = 0.f, acc1 = 0.f;
  for (int p = wave; p < NP; p += 4) {
    unsigned int u = *(const unsigned int*)(fb + (size_t)p * NH);
    float al = sm[p];
    acc0 = fmaf(al, __builtin_bit_cast(float, u << 16), acc0);
    acc1 = fmaf(al, __builtin_bit_cast(float, u & 0xFFFF0000u), acc1);
  }
  psum[wave][lane * 2] = acc0;
  psum[wave][lane * 2 + 1] = acc1;
  __syncthreads();
  if (tid < 128) {
    int e = ec * 128 + tid;
    float s = psum[0][tid] + psum[1][tid] + psum[2][tid] + psum[3][tid];
    float gate = sigf(abuf[(size_t)b * 3072 + 512 + e]);
    awe[b * NH + e] = f2bf(gate * s);
  }
}

// ---------------- KC: gates GEMM + LSTM pointwise (fused) ----------------
__global__ void k_gates_lstm(const short* __restrict__ awe_bf, const short* __restrict__ w_ih,
                             const float* __restrict__ xp, const float* __restrict__ abuf,
                             const int* __restrict__ lengths, float* __restrict__ cbuf,
                             short* __restrict__ hbuf, short* __restrict__ hnall, int t) {
  int tid = threadIdx.x, wave = tid >> 6, lane = tid & 63;
  int rlo = lane & 15, quad = lane >> 4;
  int n = wave * 512 + blockIdx.x * 16 + rlo;  // gate g=wave, 16-col slice
  const short* brow = w_ih + (size_t)n * 1024 + 512 + quad * 8;
  const short* arow = awe_bf + rlo * 512 + quad * 8;
  floatx4 acc[8];
#pragma unroll
  for (int mt = 0; mt < 8; ++mt) acc[mt] = (floatx4){0.f, 0.f, 0.f, 0.f};
  for (int k = 0; k < 512; k += 32) {
    short8 bfr = *(const short8*)(brow + k);
#pragma unroll
    for (int mt = 0; mt < 8; ++mt) {
      short8 afr = *(const short8*)(arow + mt * (16 * 512) + k);
      acc[mt] = __builtin_amdgcn_mfma_f32_16x16x32_bf16(afr, bfr, acc[mt], 0, 0, 0);
    }
  }
  __shared__ float gsm[4][128][17];  // +1 pad: kill bank conflicts
#pragma unroll
  for (int mt = 0; mt < 8; ++mt)
#pragma unroll
    for (int r = 0; r < 4; ++r) {
      int bb = mt * 16 + quad * 4 + r;
      float v = acc[mt][r] + xp[((size_t)t * 128 + bb) * 2048 + n] + abuf[(size_t)bb * 3072 + 1024 + n];
      gsm[wave][bb][rlo] = v;
    }
  __syncthreads();
  for (int idx = tid; idx < 2048; idx += 256) {
    int bb = idx >> 4, jl = idx & 15;
    int j = blockIdx.x * 16 + jl;
    float ig = gsm[0][bb][jl], fg = gsm[1][bb][jl], gg = gsm[2][bb][jl], og = gsm[3][bb][jl];
    float co = cbuf[bb * 512 + j];
    float cn = sigf(fg) * co + sigf(ig) * tanhf(gg);
    float hn = sigf(og) * tanhf(cn);
    hnall[(size_t)t * (128 * 512) + bb * 512 + j] = f2bf(hn);
    if (t < lengths[bb] - 1) {
      cbuf[bb * 512 + j] = cn;
      hbuf[bb * 512 + j] = f2bf(hn);
    }
  }
}

// ---------------- batched preds: [2432 x 32000 x 512] GEMM, w_fc read once ----------------
__global__ void k_preds_all(const short* __restrict__ hnall, const short* __restrict__ w_fc,
                            const void* __restrict__ b_fc, const int* __restrict__ lengths,
                            void* __restrict__ d_out, const int* __restrict__ flagp) {
  int fl = *flagp;
  int tid = threadIdx.x, wave = tid >> 6, lane = tid & 63;
  int rlo = lane & 15, quad = lane >> 4;
  int n0 = blockIdx.x * 128;
  int mh = (wave >> 1) * 64;  // wave's m-half: 0 or 64
  int nh = (wave & 1) * 64;   // wave's n-half: 0 or 64
  __shared__ short Al[128 * 128];  // 32 KB, XOR-swizzled rows
  __shared__ short Bl[128 * 128];  // 32 KB, XOR-swizzled rows

  float bias[4];
#pragma unroll
  for (int nf = 0; nf < 4; ++nf) bias[nf] = ldw(fl, b_fc, n0 + nh + nf * 16 + rlo);

  for (int t = 0; t < NT; ++t) {
    floatx4 acc[4][4];
#pragma unroll
    for (int mt = 0; mt < 4; ++mt)
#pragma unroll
      for (int nf = 0; nf < 4; ++nf) acc[mt][nf] = (floatx4){0.f, 0.f, 0.f, 0.f};

    for (int kc = 0; kc < 4; ++kc) {
#pragma unroll
      for (int j = 0; j < 8; ++j) {
        int idx = j * 256 + tid;  // 0..2047
        int row = idx >> 4, c8 = idx & 15;
        int sw = (c8 * 16) ^ ((row & 7) << 4);  // swizzled byte offset within row
        short8 va = *(const short8*)(hnall + ((size_t)t * 128 + row) * 512 + kc * 128 + c8 * 8);
        *(short8*)((char*)Al + row * 256 + sw) = va;
        short8 vb = *(const short8*)(w_fc + (size_t)(n0 + row) * 512 + kc * 128 + c8 * 8);
        *(short8*)((char*)Bl + row * 256 + sw) = vb;
      }
      __syncthreads();
#pragma unroll
      for (int kkl = 0; kkl < 4; ++kkl) {
        int kb = kkl * 64 + quad * 16;  // byte offset of this lane's k-slice
        short8 afr[4], bfr[4];
#pragma unroll
        for (int mt = 0; mt < 4; ++mt) {
          int row = mh + mt * 16 + rlo;
          afr[mt] = *(const short8*)((const char*)Al + row * 256 + (kb ^ ((row & 7) << 4)));
        }
#pragma unroll
        for (int nf = 0; nf < 4; ++nf) {
          int row = nh + nf * 16 + rlo;
          bfr[nf] = *(const short8*)((const char*)Bl + row * 256 + (kb ^ ((row & 7) << 4)));
        }
#pragma unroll
        for (int mt = 0; mt < 4; ++mt)
#pragma unroll
          for (int nf = 0; nf < 4; ++nf)
            acc[mt][nf] = __builtin_amdgcn_mfma_f32_16x16x32_bf16(afr[mt], bfr[nf], acc[mt][nf], 0, 0, 0);
      }
      __syncthreads();
    }
#pragma unroll
    for (int mt = 0; mt < 4; ++mt)
#pragma unroll
      for (int r = 0; r < 4; ++r) {
        int bb = mh + mt * 16 + quad * 4 + r;
        bool act = t < lengths[bb] - 1;
#pragma unroll
        for (int nf = 0; nf < 4; ++nf) {
          int n = n0 + nh + nf * 16 + rlo;
          float v = act ? (acc[mt][nf][r] + bias[nf]) : 0.f;
          size_t oi = ((size_t)bb * NT + t) * NV + n;
          if (fl) ((short*)d_out)[oi] = f2bf(v);
          else ((float*)d_out)[oi] = v;
        }
      }
  }
}

extern "C" void kernel_launch(void* const* d_in, const int* in_sizes, int n_in,
                              void* d_out, int out_size, void* d_ws, size_t ws_size,
                              hipStream_t stream) {
  const void* features = d_in[0];
  const int* captions = (const int*)d_in[1];
  const int* lengths = (const int*)d_in[2];
  const void* w_enc_att = d_in[3];
  const void* b_enc_att = d_in[4];
  const void* w_dec_att = d_in[5];
  const void* b_dec_att = d_in[6];
  const void* w_full = d_in[7];
  const void* embed_w = d_in[9];
  const void* w_ih = d_in[10];
  const void* b_ih = d_in[11];
  const void* w_hh = d_in[12];
  const void* b_hh = d_in[13];
  const void* w_init_h = d_in[14];
  const void* b_init_h = d_in[15];
  const void* w_init_c = d_in[16];
  const void* b_init_c = d_in[17];
  const void* w_beta = d_in[18];
  const void* b_beta = d_in[19];
  const void* w_fc = d_in[20];
  const void* b_fc = d_in[21];

  char* ws = (char*)d_ws;
  int* flagp = (int*)ws; ws += 16;
  short* cfeat = (short*)ws; ws += (size_t)12845056 * 2;
  short* cembed = (short*)ws; ws += (size_t)16384000 * 2;
  short* cwfc = (short*)ws; ws += (size_t)16384000 * 2;
  short* cwih = (short*)ws; ws += (size_t)2097152 * 2;
  short* cwhh = (short*)ws; ws += (size_t)1048576 * 2;
  short* cwenc = (short*)ws; ws += (size_t)262144 * 2;
  short* cwdec = (short*)ws; ws += (size_t)262144 * 2;
  short* cwbeta = (short*)ws; ws += (size_t)262144 * 2;
  short* cwinith = (short*)ws; ws += (size_t)262144 * 2;
  short* cwinitc = (short*)ws; ws += (size_t)262144 * 2;
  short* att1 = (short*)ws; ws += (size_t)25088 * 512 * 2;
  float* xp   = (float*)ws; ws += (size_t)2432 * 2048 * 4;
  float* abuf = (float*)ws; ws += (size_t)128 * 3072 * 4;
  float* escore = (float*)ws; ws += (size_t)25088 * 4;
  short* hbuf = (short*)ws; ws += 128 * 512 * 2;
  short* hnall = (short*)ws; ws += (size_t)NT * 128 * 512 * 2;
  short* awe  = (short*)ws; ws += 128 * 512 * 2;
  short* fmean = (short*)ws; ws += 128 * 512 * 2;
  float* cbuf = (float*)ws; ws += 128 * 512 * 4;

  k_detect<<<1, 256, 0, stream>>>((const unsigned int*)features, flagp);
  k_convall<<<2048, 256, 0, stream>>>(features, embed_w, w_fc, w_ih, w_hh,
                                      w_enc_att, w_dec_att, w_beta, w_init_h, w_init_c,
                                      cfeat, flagp);

  k_fmean<<<128, 256, 0, stream>>>(cfeat, fmean);
  k_att1<<<dim3(8, 196), 256, 0, stream>>>(cfeat, cwenc, b_enc_att, att1, flagp);
  k_xpart<<<dim3(32, NT), 256, 0, stream>>>(captions, cembed, cwih, b_ih, b_hh, xp, flagp);
  k_init<<<16, 256, 0, stream>>>(fmean, cwinith, b_init_h, cwinitc, b_init_c, hbuf, cbuf, flagp);

  for (int t = 0; t < NT; ++t) {
    k_hproj<<<48, 256, 0, stream>>>(hbuf, cwdec, b_dec_att, cwbeta, b_beta, cwhh, abuf, flagp);
    k_score<<<784, 256, 0, stream>>>(att1, abuf, w_full, escore, flagp);
    k_ctx<<<dim3(4, 128), 256, 0, stream>>>(escore, cfeat, abuf, lengths, awe, d_out, flagp, t);
    k_gates_lstm<<<32, 256, 0, stream>>>(awe, cwih, xp, abuf, lengths, cbuf, hbuf, hnall, t);
  }
  k_preds_all<<<250, 256, 0, stream>>>(hnall, cwfc, b_fc, lengths, d_out, flagp);
}

// Round 3
// 2336.058 us; speedup vs baseline: 3.1866x; 1.1511x over previous
//
#include <hip/hip_runtime.h>
#include <hip/hip_bf16.h>

typedef __attribute__((ext_vector_type(8))) short short8;
typedef __attribute__((ext_vector_type(4))) float floatx4;

#define NB 128
#define NP 196
#define NH 512
#define NV 32000
#define NT 19

__device__ __forceinline__ float bf2f(short s) {
  unsigned int u = ((unsigned int)(unsigned short)s) << 16;
  return __builtin_bit_cast(float, u);
}
__device__ __forceinline__ short f2bf(float f) {
  unsigned int u = __builtin_bit_cast(unsigned int, f);
  unsigned int lsb = (u >> 16) & 1u;
  u += 0x7fffu + lsb;
  return (short)(u >> 16);
}
__device__ __forceinline__ float sigf(float x) { return 1.f / (1.f + expf(-x)); }
// dual-mode scalar load: flag=1 -> bf16, flag=0 -> f32
__device__ __forceinline__ float ldw(int fl, const void* p, int i) {
  return fl ? bf2f(((const short*)p)[i]) : ((const float*)p)[i];
}

// ---------------- detect input dtype from features bit patterns ----------------
__global__ void k_detect(const unsigned int* __restrict__ w, int* __restrict__ flagp) {
  __shared__ int cnt;
  if (threadIdx.x == 0) cnt = 0;
  __syncthreads();
  int local = 0;
  for (int i = threadIdx.x; i < 4096; i += 256) {
    unsigned int lo = w[i] & 0xFFFFu;
    unsigned int ex = (lo >> 7) & 0xFFu;
    if (ex >= 110u && ex <= 135u) local++;
  }
  atomicAdd(&cnt, local);
  __syncthreads();
  if (threadIdx.x == 0) *flagp = (cnt > 2048) ? 1 : 0;
}

// ---------------- single merged convert kernel: 10 tensors -> contiguous bf16 ws ----------------
__global__ void k_convall(const void* __restrict__ s0, const void* __restrict__ s1,
                          const void* __restrict__ s2, const void* __restrict__ s3,
                          const void* __restrict__ s4, const void* __restrict__ s5,
                          const void* __restrict__ s6, const void* __restrict__ s7,
                          const void* __restrict__ s8, const void* __restrict__ s9,
                          short* __restrict__ dst, const int* __restrict__ flagp) {
  int fl = *flagp;
  const int totc = 50069504 / 8;  // total short8 chunks
  for (int c = blockIdx.x * 256 + threadIdx.x; c < totc; c += gridDim.x * 256) {
    int i = c * 8;
    const void* src;
    int off;
    if (i < 12845056)      { src = s0; off = i; }
    else if (i < 29229056) { src = s1; off = i - 12845056; }
    else if (i < 45613056) { src = s2; off = i - 29229056; }
    else if (i < 47710208) { src = s3; off = i - 45613056; }
    else if (i < 48758784) { src = s4; off = i - 47710208; }
    else if (i < 49020928) { src = s5; off = i - 48758784; }
    else if (i < 49283072) { src = s6; off = i - 49020928; }
    else if (i < 49545216) { src = s7; off = i - 49283072; }
    else if (i < 49807360) { src = s8; off = i - 49545216; }
    else                   { src = s9; off = i - 49807360; }
    if (fl) {
      ((short8*)dst)[c] = *(const short8*)((const short*)src + off);
    } else {
      const float* sp = (const float*)src + off;
      short8 o;
#pragma unroll
      for (int j = 0; j < 8; ++j) o[j] = f2bf(sp[j]);
      ((short8*)dst)[c] = o;
    }
  }
}

// ---------------- K0: fmean = mean_p features ----------------
__global__ void k_fmean(const short* __restrict__ feat, short* __restrict__ fmean) {
  int b = blockIdx.x;
  for (int e = threadIdx.x; e < NH; e += 256) {
    float s = 0.f;
    const short* fp = feat + (size_t)b * (NP * NH) + e;
    for (int p = 0; p < NP; ++p) s += bf2f(fp[p * NH]);
    fmean[b * NH + e] = f2bf(s * (1.f / 196.f));
  }
}

// ---------------- K1: h0/c0 init (M=128,N=1024,K=512) ----------------
__global__ void k_init(const short* __restrict__ fmean,
                       const short* __restrict__ w_init_h, const void* __restrict__ b_init_h,
                       const short* __restrict__ w_init_c, const void* __restrict__ b_init_c,
                       short* __restrict__ hbuf, float* __restrict__ cbuf,
                       const int* __restrict__ flagp) {
  int fl = *flagp;
  int wave = threadIdx.x >> 6, lane = threadIdx.x & 63;
  int rlo = lane & 15, quad = lane >> 4;
  int n = (blockIdx.x * 4 + wave) * 16 + rlo;
  const short* brow = (n < 512 ? w_init_h + (size_t)n * 512 : w_init_c + (size_t)(n - 512) * 512) + quad * 8;
  const short* arow = fmean + rlo * 512 + quad * 8;
  floatx4 acc[8];
#pragma unroll
  for (int mt = 0; mt < 8; ++mt) acc[mt] = (floatx4){0.f, 0.f, 0.f, 0.f};
  for (int k = 0; k < 512; k += 32) {
    short8 bfr = *(const short8*)(brow + k);
#pragma unroll
    for (int mt = 0; mt < 8; ++mt) {
      short8 afr = *(const short8*)(arow + mt * (16 * 512) + k);
      acc[mt] = __builtin_amdgcn_mfma_f32_16x16x32_bf16(afr, bfr, acc[mt], 0, 0, 0);
    }
  }
  float bias = (n < 512) ? ldw(fl, b_init_h, n) : ldw(fl, b_init_c, n - 512);
#pragma unroll
  for (int mt = 0; mt < 8; ++mt)
#pragma unroll
    for (int r = 0; r < 4; ++r) {
      int bb = mt * 16 + quad * 4 + r;
      float v = acc[mt][r] + bias;
      if (n < 512) hbuf[bb * 512 + n] = f2bf(v);
      else cbuf[bb * 512 + (n - 512)] = v;
    }
}

// ---------------- K2: att1 = features @ w_enc^T + b (M=25088,N=512,K=512) ----------------
__global__ void k_att1(const short* __restrict__ feat, const short* __restrict__ w_enc,
                       const void* __restrict__ b_enc, short* __restrict__ att1,
                       const int* __restrict__ flagp) {
  int fl = *flagp;
  int wave = threadIdx.x >> 6, lane = threadIdx.x & 63;
  int rlo = lane & 15, quad = lane >> 4;
  int n = (blockIdx.x * 4 + wave) * 16 + rlo;
  int mbase = blockIdx.y * 128;
  const short* brow = w_enc + (size_t)n * 512 + quad * 8;
  const short* arow = feat + (size_t)(mbase + rlo) * 512 + quad * 8;
  floatx4 acc[8];
#pragma unroll
  for (int mt = 0; mt < 8; ++mt) acc[mt] = (floatx4){0.f, 0.f, 0.f, 0.f};
  for (int k = 0; k < 512; k += 32) {
    short8 bfr = *(const short8*)(brow + k);
#pragma unroll
    for (int mt = 0; mt < 8; ++mt) {
      short8 afr = *(const short8*)(arow + (size_t)mt * (16 * 512) + k);
      acc[mt] = __builtin_amdgcn_mfma_f32_16x16x32_bf16(afr, bfr, acc[mt], 0, 0, 0);
    }
  }
  float bias = ldw(fl, b_enc, n);
#pragma unroll
  for (int mt = 0; mt < 8; ++mt)
#pragma unroll
    for (int r = 0; r < 4; ++r) {
      int m = mbase + mt * 16 + quad * 4 + r;
      att1[(size_t)m * 512 + n] = f2bf(acc[mt][r] + bias);
    }
}

// ---------------- K3: xpart[t,b,:] = emb @ w_ih[:, :512]^T + b_ih + b_hh ----------------
__global__ void k_xpart(const int* __restrict__ captions, const short* __restrict__ embed_w,
                        const short* __restrict__ w_ih, const void* __restrict__ b_ih,
                        const void* __restrict__ b_hh, float* __restrict__ xp,
                        const int* __restrict__ flagp) {
  int fl = *flagp;
  int wave = threadIdx.x >> 6, lane = threadIdx.x & 63;
  int rlo = lane & 15, quad = lane >> 4;
  int t = blockIdx.y;
  int n = (blockIdx.x * 4 + wave) * 16 + rlo;
  const short* brow = w_ih + (size_t)n * 1024 + quad * 8;
  int tok[8];
#pragma unroll
  for (int mt = 0; mt < 8; ++mt) tok[mt] = captions[(mt * 16 + rlo) * 20 + t];
  floatx4 acc[8];
#pragma unroll
  for (int mt = 0; mt < 8; ++mt) acc[mt] = (floatx4){0.f, 0.f, 0.f, 0.f};
  for (int k = 0; k < 512; k += 32) {
    short8 bfr = *(const short8*)(brow + k);
#pragma unroll
    for (int mt = 0; mt < 8; ++mt) {
      short8 afr = *(const short8*)(embed_w + (size_t)tok[mt] * 512 + quad * 8 + k);
      acc[mt] = __builtin_amdgcn_mfma_f32_16x16x32_bf16(afr, bfr, acc[mt], 0, 0, 0);
    }
  }
  float bias = ldw(fl, b_ih, n) + ldw(fl, b_hh, n);
#pragma unroll
  for (int mt = 0; mt < 8; ++mt)
#pragma unroll
    for (int r = 0; r < 4; ++r) {
      int bb = mt * 16 + quad * 4 + r;
      xp[((size_t)t * 128 + bb) * 2048 + n] = acc[mt][r] + bias;
    }
}

// ---------------- KA: abuf = h @ [w_dec|w_beta|w_hh]^T (+biases) ----------------
__global__ void k_hproj(const short* __restrict__ hbuf,
                        const short* __restrict__ w_dec, const void* __restrict__ b_dec,
                        const short* __restrict__ w_beta, const void* __restrict__ b_beta,
                        const short* __restrict__ w_hh, float* __restrict__ abuf,
                        const int* __restrict__ flagp) {
  int fl = *flagp;
  int wave = threadIdx.x >> 6, lane = threadIdx.x & 63;
  int rlo = lane & 15, quad = lane >> 4;
  int n = (blockIdx.x * 4 + wave) * 16 + rlo;  // 0..3071
  const short* brow;
  float bias;
  if (n < 512)       { brow = w_dec  + (size_t)n * 512;          bias = ldw(fl, b_dec, n); }
  else if (n < 1024) { brow = w_beta + (size_t)(n - 512) * 512;  bias = ldw(fl, b_beta, n - 512); }
  else               { brow = w_hh   + (size_t)(n - 1024) * 512; bias = 0.f; }
  brow += quad * 8;
  const short* arow = hbuf + rlo * 512 + quad * 8;
  floatx4 acc[8];
#pragma unroll
  for (int mt = 0; mt < 8; ++mt) acc[mt] = (floatx4){0.f, 0.f, 0.f, 0.f};
  for (int k = 0; k < 512; k += 32) {
    short8 bfr = *(const short8*)(brow + k);
#pragma unroll
    for (int mt = 0; mt < 8; ++mt) {
      short8 afr = *(const short8*)(arow + mt * (16 * 512) + k);
      acc[mt] = __builtin_amdgcn_mfma_f32_16x16x32_bf16(afr, bfr, acc[mt], 0, 0, 0);
    }
  }
#pragma unroll
  for (int mt = 0; mt < 8; ++mt)
#pragma unroll
    for (int r = 0; r < 4; ++r) {
      int bb = mt * 16 + quad * 4 + r;
      abuf[(size_t)bb * 3072 + n] = acc[mt][r] + bias;
    }
}

// ---------------- KB1: scores e[b,p] for all 25088 rows, full-GPU grid ----------------
__global__ void k_score(const short* __restrict__ att1, const float* __restrict__ abuf,
                        const void* __restrict__ w_full, float* __restrict__ escore,
                        const int* __restrict__ flagp) {
  int fl = *flagp;
  int wave = threadIdx.x >> 6, lane = threadIdx.x & 63;
  int gw = blockIdx.x * 4 + wave;  // 0..3135
  int r0 = gw * 8;
  float wfr[8];
#pragma unroll
  for (int j = 0; j < 8; ++j) wfr[j] = ldw(fl, w_full, lane * 8 + j);
#pragma unroll
  for (int rr = 0; rr < 8; ++rr) {
    int r = r0 + rr;      // 0..25087
    int b = r / 196;
    const float* a2 = abuf + (size_t)b * 3072 + lane * 8;
    floatx4 a2a = *(const floatx4*)a2;
    floatx4 a2b = *(const floatx4*)(a2 + 4);
    short8 v = *(const short8*)(att1 + (size_t)r * 512 + lane * 8);
    float s = 0.f;
    s += fmaxf(bf2f(v[0]) + a2a[0], 0.f) * wfr[0];
    s += fmaxf(bf2f(v[1]) + a2a[1], 0.f) * wfr[1];
    s += fmaxf(bf2f(v[2]) + a2a[2], 0.f) * wfr[2];
    s += fmaxf(bf2f(v[3]) + a2a[3], 0.f) * wfr[3];
    s += fmaxf(bf2f(v[4]) + a2b[0], 0.f) * wfr[4];
    s += fmaxf(bf2f(v[5]) + a2b[1], 0.f) * wfr[5];
    s += fmaxf(bf2f(v[6]) + a2b[2], 0.f) * wfr[6];
    s += fmaxf(bf2f(v[7]) + a2b[3], 0.f) * wfr[7];
#pragma unroll
    for (int off = 32; off >= 1; off >>= 1) s += __shfl_xor(s, off, 64);
    if (lane == 0) escore[r] = s;
  }
}

// ---------------- KB2: softmax (redundant per block) + context chunk + gate ----------------
__global__ void k_ctx(const float* __restrict__ escore, const short* __restrict__ feat,
                      const float* __restrict__ abuf, const int* __restrict__ lengths,
                      short* __restrict__ awe, void* __restrict__ d_out,
                      const int* __restrict__ flagp, int t) {
  int fl = *flagp;
  int ec = blockIdx.x;  // 0..3
  int b = blockIdx.y;   // 0..127
  int tid = threadIdx.x, wave = tid >> 6, lane = tid & 63;
  __shared__ float sm[196];
  __shared__ float psum[4][128];
  for (int p = tid; p < NP; p += 256) sm[p] = escore[b * NP + p];
  __syncthreads();
  bool act = t < (lengths[b] - 1);
  if (wave == 0) {
    float v0 = sm[lane], v1 = sm[lane + 64], v2 = sm[lane + 128];
    float v3 = (lane < 4) ? sm[lane + 192] : -1e30f;
    float m = fmaxf(fmaxf(v0, v1), fmaxf(v2, v3));
#pragma unroll
    for (int off = 32; off >= 1; off >>= 1) m = fmaxf(m, __shfl_xor(m, off, 64));
    float e0 = expf(v0 - m), e1 = expf(v1 - m), e2 = expf(v2 - m);
    float e3 = (lane < 4) ? expf(v3 - m) : 0.f;
    float s = e0 + e1 + e2 + e3;
#pragma unroll
    for (int off = 32; off >= 1; off >>= 1) s += __shfl_xor(s, off, 64);
    float inv = 1.f / s;
    float a0 = e0 * inv, a1 = e1 * inv, a2 = e2 * inv, a3 = e3 * inv;
    sm[lane] = a0; sm[lane + 64] = a1; sm[lane + 128] = a2;
    if (lane < 4) sm[lane + 192] = a3;
    if (ec == 0) {
      size_t ob = (size_t)NB * NT * NV + ((size_t)b * NT + t) * NP;
      float o0 = act ? a0 : 0.f, o1 = act ? a1 : 0.f, o2 = act ? a2 : 0.f, o3 = act ? a3 : 0.f;
      if (fl) {
        short* op = (short*)d_out;
        op[ob + lane] = f2bf(o0); op[ob + lane + 64] = f2bf(o1); op[ob + lane + 128] = f2bf(o2);
        if (lane < 4) op[ob + lane + 192] = f2bf(o3);
      } else {
        float* op = (float*)d_out;
        op[ob + lane] = o0; op[ob + lane + 64] = o1; op[ob + lane + 128] = o2;
        if (lane < 4) op[ob + lane + 192] = o3;
      }
    }
  }
  __syncthreads();
  int eoff = ec * 128 + lane * 2;
  const short* fb = feat + (size_t)b * (NP * NH) + eoff;
  float acc0 = 0.f, acc1 = 0.f;
  for (int p = wave; p < NP; p += 4) {
    unsigned int u = *(const unsigned int*)(fb + (size_t)p * NH);
    float al = sm[p];
    acc0 = fmaf(al, __builtin_bit_cast(float, u << 16), acc0);
    acc1 = fmaf(al, __builtin_bit_cast(float, u & 0xFFFF0000u), acc1);
  }
  psum[wave][lane * 2] = acc0;
  psum[wave][lane * 2 + 1] = acc1;
  __syncthreads();
  if (tid < 128) {
    int e = ec * 128 + tid;
    float s = psum[0][tid] + psum[1][tid] + psum[2][tid] + psum[3][tid];
    float gate = sigf(abuf[(size_t)b * 3072 + 512 + e]);
    awe[b * NH + e] = f2bf(gate * s);
  }
}

// ---------------- KC: gates GEMM + LSTM pointwise (fused) ----------------
__global__ void k_gates_lstm(const short* __restrict__ awe_bf, const short* __restrict__ w_ih,
                             const float* __restrict__ xp, const float* __restrict__ abuf,
                             const int* __restrict__ lengths, float* __restrict__ cbuf,
                             short* __restrict__ hbuf, short* __restrict__ hnall, int t) {
  int tid = threadIdx.x, wave = tid >> 6, lane = tid & 63;
  int rlo = lane & 15, quad = lane >> 4;
  int n = wave * 512 + blockIdx.x * 16 + rlo;  // gate g=wave, 16-col slice
  const short* brow = w_ih + (size_t)n * 1024 + 512 + quad * 8;
  const short* arow = awe_bf + rlo * 512 + quad * 8;
  floatx4 acc[8];
#pragma unroll
  for (int mt = 0; mt < 8; ++mt) acc[mt] = (floatx4){0.f, 0.f, 0.f, 0.f};
  for (int k = 0; k < 512; k += 32) {
    short8 bfr = *(const short8*)(brow + k);
#pragma unroll
    for (int mt = 0; mt < 8; ++mt) {
      short8 afr = *(const short8*)(arow + mt * (16 * 512) + k);
      acc[mt] = __builtin_amdgcn_mfma_f32_16x16x32_bf16(afr, bfr, acc[mt], 0, 0, 0);
    }
  }
  __shared__ float gsm[4][128][17];  // +1 pad: kill bank conflicts
#pragma unroll
  for (int mt = 0; mt < 8; ++mt)
#pragma unroll
    for (int r = 0; r < 4; ++r) {
      int bb = mt * 16 + quad * 4 + r;
      float v = acc[mt][r] + xp[((size_t)t * 128 + bb) * 2048 + n] + abuf[(size_t)bb * 3072 + 1024 + n];
      gsm[wave][bb][rlo] = v;
    }
  __syncthreads();
  for (int idx = tid; idx < 2048; idx += 256) {
    int bb = idx >> 4, jl = idx & 15;
    int j = blockIdx.x * 16 + jl;
    float ig = gsm[0][bb][jl], fg = gsm[1][bb][jl], gg = gsm[2][bb][jl], og = gsm[3][bb][jl];
    float co = cbuf[bb * 512 + j];
    float cn = sigf(fg) * co + sigf(ig) * tanhf(gg);
    float hn = sigf(og) * tanhf(cn);
    hnall[(size_t)t * (128 * 512) + bb * 512 + j] = f2bf(hn);
    if (t < lengths[bb] - 1) {
      cbuf[bb * 512 + j] = cn;
      hbuf[bb * 512 + j] = f2bf(hn);
    }
  }
}

// ---------------- batched preds v2: w_fc staged in LDS ONCE per block ----------------
// grid 500 n-tiles of 64 cols; B slice (64x512 bf16 = 64KB LDS) staged once, t-loop reads
// A (hnall, 2.5MB, L2-resident) direct from global; nontemporal stores (no write-allocate)
__global__ void __launch_bounds__(256, 2)
k_preds_all(const short* __restrict__ hnall, const short* __restrict__ w_fc,
            const void* __restrict__ b_fc, const int* __restrict__ lengths,
            void* __restrict__ d_out, const int* __restrict__ flagp) {
  int fl = *flagp;
  int tid = threadIdx.x, wave = tid >> 6, lane = tid & 63;
  int rlo = lane & 15, quad = lane >> 4;
  int n0 = blockIdx.x * 64;
  int mw = wave * 32;  // each wave owns 32 m-rows, all 64 n-cols
  __shared__ short Bl[64 * 512];  // 64 KB, row-swizzled

  // stage B once: w_fc rows n0..n0+63, full K
#pragma unroll
  for (int j = 0; j < 16; ++j) {
    int idx = j * 256 + tid;        // 0..4095 chunks of 8 shorts
    int row = idx >> 6, c8 = idx & 63;
    int sw = (c8 * 16) ^ ((row & 7) << 4);
    short8 vb = *(const short8*)(w_fc + (size_t)(n0 + row) * 512 + c8 * 8);
    *(short8*)((char*)Bl + row * 1024 + sw) = vb;
  }
  __syncthreads();

  float bias[4];
  int lenr[2][4];
#pragma unroll
  for (int nf = 0; nf < 4; ++nf) bias[nf] = ldw(fl, b_fc, n0 + nf * 16 + rlo);
#pragma unroll
  for (int mt = 0; mt < 2; ++mt)
#pragma unroll
    for (int r = 0; r < 4; ++r) lenr[mt][r] = lengths[mw + mt * 16 + quad * 4 + r];

  for (int t = 0; t < NT; ++t) {
    floatx4 acc[2][4];
#pragma unroll
    for (int mt = 0; mt < 2; ++mt)
#pragma unroll
      for (int nf = 0; nf < 4; ++nf) acc[mt][nf] = (floatx4){0.f, 0.f, 0.f, 0.f};
    const short* abase = hnall + (size_t)t * (128 * 512);
#pragma unroll
    for (int ks = 0; ks < 16; ++ks) {
      short8 afr[2], bfr[4];
#pragma unroll
      for (int mt = 0; mt < 2; ++mt)
        afr[mt] = *(const short8*)(abase + (size_t)(mw + mt * 16 + rlo) * 512 + ks * 32 + quad * 8);
#pragma unroll
      for (int nf = 0; nf < 4; ++nf) {
        int row = nf * 16 + rlo;
        bfr[nf] = *(const short8*)((const char*)Bl + row * 1024 +
                                   ((ks * 64 + quad * 16) ^ ((row & 7) << 4)));
      }
#pragma unroll
      for (int mt = 0; mt < 2; ++mt)
#pragma unroll
        for (int nf = 0; nf < 4; ++nf)
          acc[mt][nf] = __builtin_amdgcn_mfma_f32_16x16x32_bf16(afr[mt], bfr[nf], acc[mt][nf], 0, 0, 0);
    }
    // epilogue: bias + mask + nontemporal store
#pragma unroll
    for (int mt = 0; mt < 2; ++mt)
#pragma unroll
      for (int r = 0; r < 4; ++r) {
        int bb = mw + mt * 16 + quad * 4 + r;
        bool act = t < lenr[mt][r] - 1;
#pragma unroll
        for (int nf = 0; nf < 4; ++nf) {
          int n = n0 + nf * 16 + rlo;
          float v = act ? (acc[mt][nf][r] + bias[nf]) : 0.f;
          size_t oi = ((size_t)bb * NT + t) * NV + n;
          if (fl) __builtin_nontemporal_store(f2bf(v), &((short*)d_out)[oi]);
          else __builtin_nontemporal_store(v, &((float*)d_out)[oi]);
        }
      }
  }
}

extern "C" void kernel_launch(void* const* d_in, const int* in_sizes, int n_in,
                              void* d_out, int out_size, void* d_ws, size_t ws_size,
                              hipStream_t stream) {
  const void* features = d_in[0];
  const int* captions = (const int*)d_in[1];
  const int* lengths = (const int*)d_in[2];
  const void* w_enc_att = d_in[3];
  const void* b_enc_att = d_in[4];
  const void* w_dec_att = d_in[5];
  const void* b_dec_att = d_in[6];
  const void* w_full = d_in[7];
  const void* embed_w = d_in[9];
  const void* w_ih = d_in[10];
  const void* b_ih = d_in[11];
  const void* w_hh = d_in[12];
  const void* b_hh = d_in[13];
  const void* w_init_h = d_in[14];
  const void* b_init_h = d_in[15];
  const void* w_init_c = d_in[16];
  const void* b_init_c = d_in[17];
  const void* w_beta = d_in[18];
  const void* b_beta = d_in[19];
  const void* w_fc = d_in[20];
  const void* b_fc = d_in[21];

  char* ws = (char*)d_ws;
  int* flagp = (int*)ws; ws += 16;
  short* cfeat = (short*)ws; ws += (size_t)12845056 * 2;
  short* cembed = (short*)ws; ws += (size_t)16384000 * 2;
  short* cwfc = (short*)ws; ws += (size_t)16384000 * 2;
  short* cwih = (short*)ws; ws += (size_t)2097152 * 2;
  short* cwhh = (short*)ws; ws += (size_t)1048576 * 2;
  short* cwenc = (short*)ws; ws += (size_t)262144 * 2;
  short* cwdec = (short*)ws; ws += (size_t)262144 * 2;
  short* cwbeta = (short*)ws; ws += (size_t)262144 * 2;
  short* cwinith = (short*)ws; ws += (size_t)262144 * 2;
  short* cwinitc = (short*)ws; ws += (size_t)262144 * 2;
  short* att1 = (short*)ws; ws += (size_t)25088 * 512 * 2;
  float* xp   = (float*)ws; ws += (size_t)2432 * 2048 * 4;
  float* abuf = (float*)ws; ws += (size_t)128 * 3072 * 4;
  float* escore = (float*)ws; ws += (size_t)25088 * 4;
  short* hbuf = (short*)ws; ws += 128 * 512 * 2;
  short* hnall = (short*)ws; ws += (size_t)NT * 128 * 512 * 2;
  short* awe  = (short*)ws; ws += 128 * 512 * 2;
  short* fmean = (short*)ws; ws += 128 * 512 * 2;
  float* cbuf = (float*)ws; ws += 128 * 512 * 4;

  k_detect<<<1, 256, 0, stream>>>((const unsigned int*)features, flagp);
  k_convall<<<2048, 256, 0, stream>>>(features, embed_w, w_fc, w_ih, w_hh,
                                      w_enc_att, w_dec_att, w_beta, w_init_h, w_init_c,
                                      cfeat, flagp);

  k_fmean<<<128, 256, 0, stream>>>(cfeat, fmean);
  k_att1<<<dim3(8, 196), 256, 0, stream>>>(cfeat, cwenc, b_enc_att, att1, flagp);
  k_xpart<<<dim3(32, NT), 256, 0, stream>>>(captions, cembed, cwih, b_ih, b_hh, xp, flagp);
  k_init<<<16, 256, 0, stream>>>(fmean, cwinith, b_init_h, cwinitc, b_init_c, hbuf, cbuf, flagp);

  for (int t = 0; t < NT; ++t) {
    k_hproj<<<48, 256, 0, stream>>>(hbuf, cwdec, b_dec_att, cwbeta, b_beta, cwhh, abuf, flagp);
    k_score<<<784, 256, 0, stream>>>(att1, abuf, w_full, escore, flagp);
    k_ctx<<<dim3(4, 128), 256, 0, stream>>>(escore, cfeat, abuf, lengths, awe, d_out, flagp, t);
    k_gates_lstm<<<32, 256, 0, stream>>>(awe, cwih, xp, abuf, lengths, cbuf, hbuf, hnall, t);
  }
  k_preds_all<<<500, 256, 0, stream>>>(hnall, cwfc, b_fc, lengths, d_out, flagp);
}

// Round 4
// 2161.019 us; speedup vs baseline: 3.4447x; 1.0810x over previous
//
#include <hip/hip_runtime.h>
#include <hip/hip_bf16.h>

typedef __attribute__((ext_vector_type(8))) short short8;
typedef __attribute__((ext_vector_type(4))) short short4v;
typedef __attribute__((ext_vector_type(4))) float floatx4;

#define NB 128
#define NP 196
#define NH 512
#define NV 32000
#define NT 19

__device__ __forceinline__ float bf2f(short s) {
  unsigned int u = ((unsigned int)(unsigned short)s) << 16;
  return __builtin_bit_cast(float, u);
}
__device__ __forceinline__ short f2bf(float f) {
  unsigned int u = __builtin_bit_cast(unsigned int, f);
  unsigned int lsb = (u >> 16) & 1u;
  u += 0x7fffu + lsb;
  return (short)(u >> 16);
}
__device__ __forceinline__ float sigf(float x) { return 1.f / (1.f + expf(-x)); }
// dual-mode scalar load: flag=1 -> bf16, flag=0 -> f32
__device__ __forceinline__ float ldw(int fl, const void* p, int i) {
  return fl ? bf2f(((const short*)p)[i]) : ((const float*)p)[i];
}

// ---------------- detect input dtype from features bit patterns ----------------
__global__ void k_detect(const unsigned int* __restrict__ w, int* __restrict__ flagp) {
  __shared__ int cnt;
  if (threadIdx.x == 0) cnt = 0;
  __syncthreads();
  int local = 0;
  for (int i = threadIdx.x; i < 4096; i += 256) {
    unsigned int lo = w[i] & 0xFFFFu;
    unsigned int ex = (lo >> 7) & 0xFFu;
    if (ex >= 110u && ex <= 135u) local++;
  }
  atomicAdd(&cnt, local);
  __syncthreads();
  if (threadIdx.x == 0) *flagp = (cnt > 2048) ? 1 : 0;
}

// ---------------- single merged convert kernel: 10 tensors -> contiguous bf16 ws ----------------
__global__ void k_convall(const void* __restrict__ s0, const void* __restrict__ s1,
                          const void* __restrict__ s2, const void* __restrict__ s3,
                          const void* __restrict__ s4, const void* __restrict__ s5,
                          const void* __restrict__ s6, const void* __restrict__ s7,
                          const void* __restrict__ s8, const void* __restrict__ s9,
                          short* __restrict__ dst, const int* __restrict__ flagp) {
  int fl = *flagp;
  const int totc = 50069504 / 8;  // total short8 chunks
  for (int c = blockIdx.x * 256 + threadIdx.x; c < totc; c += gridDim.x * 256) {
    int i = c * 8;
    const void* src;
    int off;
    if (i < 12845056)      { src = s0; off = i; }
    else if (i < 29229056) { src = s1; off = i - 12845056; }
    else if (i < 45613056) { src = s2; off = i - 29229056; }
    else if (i < 47710208) { src = s3; off = i - 45613056; }
    else if (i < 48758784) { src = s4; off = i - 47710208; }
    else if (i < 49020928) { src = s5; off = i - 48758784; }
    else if (i < 49283072) { src = s6; off = i - 49020928; }
    else if (i < 49545216) { src = s7; off = i - 49283072; }
    else if (i < 49807360) { src = s8; off = i - 49545216; }
    else                   { src = s9; off = i - 49807360; }
    if (fl) {
      ((short8*)dst)[c] = *(const short8*)((const short*)src + off);
    } else {
      const float* sp = (const float*)src + off;
      short8 o;
#pragma unroll
      for (int j = 0; j < 8; ++j) o[j] = f2bf(sp[j]);
      ((short8*)dst)[c] = o;
    }
  }
}

// ---------------- K0: fmean = mean_p features ----------------
__global__ void k_fmean(const short* __restrict__ feat, short* __restrict__ fmean) {
  int b = blockIdx.x;
  for (int e = threadIdx.x; e < NH; e += 256) {
    float s = 0.f;
    const short* fp = feat + (size_t)b * (NP * NH) + e;
    for (int p = 0; p < NP; ++p) s += bf2f(fp[p * NH]);
    fmean[b * NH + e] = f2bf(s * (1.f / 196.f));
  }
}

// ---------------- K1: h0/c0 init (M=128,N=1024,K=512) ----------------
__global__ void k_init(const short* __restrict__ fmean,
                       const short* __restrict__ w_init_h, const void* __restrict__ b_init_h,
                       const short* __restrict__ w_init_c, const void* __restrict__ b_init_c,
                       short* __restrict__ hbuf, float* __restrict__ cbuf,
                       const int* __restrict__ flagp) {
  int fl = *flagp;
  int wave = threadIdx.x >> 6, lane = threadIdx.x & 63;
  int rlo = lane & 15, quad = lane >> 4;
  int n = (blockIdx.x * 4 + wave) * 16 + rlo;
  const short* brow = (n < 512 ? w_init_h + (size_t)n * 512 : w_init_c + (size_t)(n - 512) * 512) + quad * 8;
  const short* arow = fmean + rlo * 512 + quad * 8;
  floatx4 acc[8];
#pragma unroll
  for (int mt = 0; mt < 8; ++mt) acc[mt] = (floatx4){0.f, 0.f, 0.f, 0.f};
  for (int k = 0; k < 512; k += 32) {
    short8 bfr = *(const short8*)(brow + k);
#pragma unroll
    for (int mt = 0; mt < 8; ++mt) {
      short8 afr = *(const short8*)(arow + mt * (16 * 512) + k);
      acc[mt] = __builtin_amdgcn_mfma_f32_16x16x32_bf16(afr, bfr, acc[mt], 0, 0, 0);
    }
  }
  float bias = (n < 512) ? ldw(fl, b_init_h, n) : ldw(fl, b_init_c, n - 512);
#pragma unroll
  for (int mt = 0; mt < 8; ++mt)
#pragma unroll
    for (int r = 0; r < 4; ++r) {
      int bb = mt * 16 + quad * 4 + r;
      float v = acc[mt][r] + bias;
      if (n < 512) hbuf[bb * 512 + n] = f2bf(v);
      else cbuf[bb * 512 + (n - 512)] = v;
    }
}

// ---------------- K2: att1 = features @ w_enc^T + b (M=25088,N=512,K=512) ----------------
__global__ void k_att1(const short* __restrict__ feat, const short* __restrict__ w_enc,
                       const void* __restrict__ b_enc, short* __restrict__ att1,
                       const int* __restrict__ flagp) {
  int fl = *flagp;
  int wave = threadIdx.x >> 6, lane = threadIdx.x & 63;
  int rlo = lane & 15, quad = lane >> 4;
  int n = (blockIdx.x * 4 + wave) * 16 + rlo;
  int mbase = blockIdx.y * 128;
  const short* brow = w_enc + (size_t)n * 512 + quad * 8;
  const short* arow = feat + (size_t)(mbase + rlo) * 512 + quad * 8;
  floatx4 acc[8];
#pragma unroll
  for (int mt = 0; mt < 8; ++mt) acc[mt] = (floatx4){0.f, 0.f, 0.f, 0.f};
  for (int k = 0; k < 512; k += 32) {
    short8 bfr = *(const short8*)(brow + k);
#pragma unroll
    for (int mt = 0; mt < 8; ++mt) {
      short8 afr = *(const short8*)(arow + (size_t)mt * (16 * 512) + k);
      acc[mt] = __builtin_amdgcn_mfma_f32_16x16x32_bf16(afr, bfr, acc[mt], 0, 0, 0);
    }
  }
  float bias = ldw(fl, b_enc, n);
#pragma unroll
  for (int mt = 0; mt < 8; ++mt)
#pragma unroll
    for (int r = 0; r < 4; ++r) {
      int m = mbase + mt * 16 + quad * 4 + r;
      att1[(size_t)m * 512 + n] = f2bf(acc[mt][r] + bias);
    }
}

// ---------------- K3: xpart[t,b,:] = emb @ w_ih[:, :512]^T + b_ih + b_hh ----------------
__global__ void k_xpart(const int* __restrict__ captions, const short* __restrict__ embed_w,
                        const short* __restrict__ w_ih, const void* __restrict__ b_ih,
                        const void* __restrict__ b_hh, float* __restrict__ xp,
                        const int* __restrict__ flagp) {
  int fl = *flagp;
  int wave = threadIdx.x >> 6, lane = threadIdx.x & 63;
  int rlo = lane & 15, quad = lane >> 4;
  int t = blockIdx.y;
  int n = (blockIdx.x * 4 + wave) * 16 + rlo;
  const short* brow = w_ih + (size_t)n * 1024 + quad * 8;
  int tok[8];
#pragma unroll
  for (int mt = 0; mt < 8; ++mt) tok[mt] = captions[(mt * 16 + rlo) * 20 + t];
  floatx4 acc[8];
#pragma unroll
  for (int mt = 0; mt < 8; ++mt) acc[mt] = (floatx4){0.f, 0.f, 0.f, 0.f};
  for (int k = 0; k < 512; k += 32) {
    short8 bfr = *(const short8*)(brow + k);
#pragma unroll
    for (int mt = 0; mt < 8; ++mt) {
      short8 afr = *(const short8*)(embed_w + (size_t)tok[mt] * 512 + quad * 8 + k);
      acc[mt] = __builtin_amdgcn_mfma_f32_16x16x32_bf16(afr, bfr, acc[mt], 0, 0, 0);
    }
  }
  float bias = ldw(fl, b_ih, n) + ldw(fl, b_hh, n);
#pragma unroll
  for (int mt = 0; mt < 8; ++mt)
#pragma unroll
    for (int r = 0; r < 4; ++r) {
      int bb = mt * 16 + quad * 4 + r;
      xp[((size_t)t * 128 + bb) * 2048 + n] = acc[mt][r] + bias;
    }
}

// ---------------- KA: abuf = h @ [w_dec|w_beta|w_hh]^T (+biases) ----------------
__global__ void k_hproj(const short* __restrict__ hbuf,
                        const short* __restrict__ w_dec, const void* __restrict__ b_dec,
                        const short* __restrict__ w_beta, const void* __restrict__ b_beta,
                        const short* __restrict__ w_hh, float* __restrict__ abuf,
                        const int* __restrict__ flagp) {
  int fl = *flagp;
  int wave = threadIdx.x >> 6, lane = threadIdx.x & 63;
  int rlo = lane & 15, quad = lane >> 4;
  int n = (blockIdx.x * 4 + wave) * 16 + rlo;  // 0..3071
  const short* brow;
  float bias;
  if (n < 512)       { brow = w_dec  + (size_t)n * 512;          bias = ldw(fl, b_dec, n); }
  else if (n < 1024) { brow = w_beta + (size_t)(n - 512) * 512;  bias = ldw(fl, b_beta, n - 512); }
  else               { brow = w_hh   + (size_t)(n - 1024) * 512; bias = 0.f; }
  brow += quad * 8;
  const short* arow = hbuf + rlo * 512 + quad * 8;
  floatx4 acc[8];
#pragma unroll
  for (int mt = 0; mt < 8; ++mt) acc[mt] = (floatx4){0.f, 0.f, 0.f, 0.f};
  for (int k = 0; k < 512; k += 32) {
    short8 bfr = *(const short8*)(brow + k);
#pragma unroll
    for (int mt = 0; mt < 8; ++mt) {
      short8 afr = *(const short8*)(arow + mt * (16 * 512) + k);
      acc[mt] = __builtin_amdgcn_mfma_f32_16x16x32_bf16(afr, bfr, acc[mt], 0, 0, 0);
    }
  }
#pragma unroll
  for (int mt = 0; mt < 8; ++mt)
#pragma unroll
    for (int r = 0; r < 4; ++r) {
      int bb = mt * 16 + quad * 4 + r;
      abuf[(size_t)bb * 3072 + n] = acc[mt][r] + bias;
    }
}

// ---------------- KB1: scores e[b,p] for all 25088 rows, full-GPU grid ----------------
__global__ void k_score(const short* __restrict__ att1, const float* __restrict__ abuf,
                        const void* __restrict__ w_full, float* __restrict__ escore,
                        const int* __restrict__ flagp) {
  int fl = *flagp;
  int wave = threadIdx.x >> 6, lane = threadIdx.x & 63;
  int gw = blockIdx.x * 4 + wave;  // 0..3135
  int r0 = gw * 8;
  float wfr[8];
#pragma unroll
  for (int j = 0; j < 8; ++j) wfr[j] = ldw(fl, w_full, lane * 8 + j);
#pragma unroll
  for (int rr = 0; rr < 8; ++rr) {
    int r = r0 + rr;      // 0..25087
    int b = r / 196;
    const float* a2 = abuf + (size_t)b * 3072 + lane * 8;
    floatx4 a2a = *(const floatx4*)a2;
    floatx4 a2b = *(const floatx4*)(a2 + 4);
    short8 v = *(const short8*)(att1 + (size_t)r * 512 + lane * 8);
    float s = 0.f;
    s += fmaxf(bf2f(v[0]) + a2a[0], 0.f) * wfr[0];
    s += fmaxf(bf2f(v[1]) + a2a[1], 0.f) * wfr[1];
    s += fmaxf(bf2f(v[2]) + a2a[2], 0.f) * wfr[2];
    s += fmaxf(bf2f(v[3]) + a2a[3], 0.f) * wfr[3];
    s += fmaxf(bf2f(v[4]) + a2b[0], 0.f) * wfr[4];
    s += fmaxf(bf2f(v[5]) + a2b[1], 0.f) * wfr[5];
    s += fmaxf(bf2f(v[6]) + a2b[2], 0.f) * wfr[6];
    s += fmaxf(bf2f(v[7]) + a2b[3], 0.f) * wfr[7];
#pragma unroll
    for (int off = 32; off >= 1; off >>= 1) s += __shfl_xor(s, off, 64);
    if (lane == 0) escore[r] = s;
  }
}

// ---------------- KB2: softmax (redundant per block) + context chunk + gate ----------------
__global__ void k_ctx(const float* __restrict__ escore, const short* __restrict__ feat,
                      const float* __restrict__ abuf, const int* __restrict__ lengths,
                      short* __restrict__ awe, void* __restrict__ d_out,
                      const int* __restrict__ flagp, int t) {
  int fl = *flagp;
  int ec = blockIdx.x;  // 0..3
  int b = blockIdx.y;   // 0..127
  int tid = threadIdx.x, wave = tid >> 6, lane = tid & 63;
  __shared__ float sm[196];
  __shared__ float psum[4][128];
  for (int p = tid; p < NP; p += 256) sm[p] = escore[b * NP + p];
  __syncthreads();
  bool act = t < (lengths[b] - 1);
  if (wave == 0) {
    float v0 = sm[lane], v1 = sm[lane + 64], v2 = sm[lane + 128];
    float v3 = (lane < 4) ? sm[lane + 192] : -1e30f;
    float m = fmaxf(fmaxf(v0, v1), fmaxf(v2, v3));
#pragma unroll
    for (int off = 32; off >= 1; off >>= 1) m = fmaxf(m, __shfl_xor(m, off, 64));
    float e0 = expf(v0 - m), e1 = expf(v1 - m), e2 = expf(v2 - m);
    float e3 = (lane < 4) ? expf(v3 - m) : 0.f;
    float s = e0 + e1 + e2 + e3;
#pragma unroll
    for (int off = 32; off >= 1; off >>= 1) s += __shfl_xor(s, off, 64);
    float inv = 1.f / s;
    float a0 = e0 * inv, a1 = e1 * inv, a2 = e2 * inv, a3 = e3 * inv;
    sm[lane] = a0; sm[lane + 64] = a1; sm[lane + 128] = a2;
    if (lane < 4) sm[lane + 192] = a3;
    if (ec == 0) {
      size_t ob = (size_t)NB * NT * NV + ((size_t)b * NT + t) * NP;
      float o0 = act ? a0 : 0.f, o1 = act ? a1 : 0.f, o2 = act ? a2 : 0.f, o3 = act ? a3 : 0.f;
      if (fl) {
        short* op = (short*)d_out;
        op[ob + lane] = f2bf(o0); op[ob + lane + 64] = f2bf(o1); op[ob + lane + 128] = f2bf(o2);
        if (lane < 4) op[ob + lane + 192] = f2bf(o3);
      } else {
        float* op = (float*)d_out;
        op[ob + lane] = o0; op[ob + lane + 64] = o1; op[ob + lane + 128] = o2;
        if (lane < 4) op[ob + lane + 192] = o3;
      }
    }
  }
  __syncthreads();
  int eoff = ec * 128 + lane * 2;
  const short* fb = feat + (size_t)b * (NP * NH) + eoff;
  float acc0 = 0.f, acc1 = 0.f;
  for (int p = wave; p < NP; p += 4) {
    unsigned int u = *(const unsigned int*)(fb + (size_t)p * NH);
    float al = sm[p];
    acc0 = fmaf(al, __builtin_bit_cast(float, u << 16), acc0);
    acc1 = fmaf(al, __builtin_bit_cast(float, u & 0xFFFF0000u), acc1);
  }
  psum[wave][lane * 2] = acc0;
  psum[wave][lane * 2 + 1] = acc1;
  __syncthreads();
  if (tid < 128) {
    int e = ec * 128 + tid;
    float s = psum[0][tid] + psum[1][tid] + psum[2][tid] + psum[3][tid];
    float gate = sigf(abuf[(size_t)b * 3072 + 512 + e]);
    awe[b * NH + e] = f2bf(gate * s);
  }
}

// ---------------- KC: gates GEMM + LSTM pointwise (fused) ----------------
// hnall written K-MAJOR: hnall[t*65536 + (j>>3)*1024 + bb*8 + (j&7)]
__global__ void k_gates_lstm(const short* __restrict__ awe_bf, const short* __restrict__ w_ih,
                             const float* __restrict__ xp, const float* __restrict__ abuf,
                             const int* __restrict__ lengths, float* __restrict__ cbuf,
                             short* __restrict__ hbuf, short* __restrict__ hnall, int t) {
  int tid = threadIdx.x, wave = tid >> 6, lane = tid & 63;
  int rlo = lane & 15, quad = lane >> 4;
  int n = wave * 512 + blockIdx.x * 16 + rlo;  // gate g=wave, 16-col slice
  const short* brow = w_ih + (size_t)n * 1024 + 512 + quad * 8;
  const short* arow = awe_bf + rlo * 512 + quad * 8;
  floatx4 acc[8];
#pragma unroll
  for (int mt = 0; mt < 8; ++mt) acc[mt] = (floatx4){0.f, 0.f, 0.f, 0.f};
  for (int k = 0; k < 512; k += 32) {
    short8 bfr = *(const short8*)(brow + k);
#pragma unroll
    for (int mt = 0; mt < 8; ++mt) {
      short8 afr = *(const short8*)(arow + mt * (16 * 512) + k);
      acc[mt] = __builtin_amdgcn_mfma_f32_16x16x32_bf16(afr, bfr, acc[mt], 0, 0, 0);
    }
  }
  __shared__ float gsm[4][128][17];  // +1 pad: kill bank conflicts
#pragma unroll
  for (int mt = 0; mt < 8; ++mt)
#pragma unroll
    for (int r = 0; r < 4; ++r) {
      int bb = mt * 16 + quad * 4 + r;
      float v = acc[mt][r] + xp[((size_t)t * 128 + bb) * 2048 + n] + abuf[(size_t)bb * 3072 + 1024 + n];
      gsm[wave][bb][rlo] = v;
    }
  __syncthreads();
  for (int idx = tid; idx < 2048; idx += 256) {
    int bb = idx >> 4, jl = idx & 15;
    int j = blockIdx.x * 16 + jl;
    float ig = gsm[0][bb][jl], fg = gsm[1][bb][jl], gg = gsm[2][bb][jl], og = gsm[3][bb][jl];
    float co = cbuf[bb * 512 + j];
    float cn = sigf(fg) * co + sigf(ig) * tanhf(gg);
    float hn = sigf(og) * tanhf(cn);
    hnall[(size_t)t * 65536 + (j >> 3) * 1024 + bb * 8 + (j & 7)] = f2bf(hn);
    if (t < lengths[bb] - 1) {
      cbuf[bb * 512 + j] = cn;
      hbuf[bb * 512 + j] = f2bf(hn);
    }
  }
}

// ---------------- batched preds v3: B in LDS once; A k-major reg-batched; full-line stores ----------------
// grid 500 n-tiles of 64 cols; per t: preload all A (32 dwordx4 burst) -> pure LDS+MFMA loop ->
// LDS-staged epilogue so every store instruction covers full 128B lines (no RMW fetch)
__global__ void __launch_bounds__(256, 2)
k_preds_all(const short* __restrict__ hnall, const short* __restrict__ w_fc,
            const void* __restrict__ b_fc, const int* __restrict__ lengths,
            void* __restrict__ d_out, const int* __restrict__ flagp) {
  int fl = *flagp;
  int tid = threadIdx.x, wave = tid >> 6, lane = tid & 63;
  int rlo = lane & 15, quad = lane >> 4;
  int n0 = blockIdx.x * 64;
  int mw = wave * 32;  // each wave owns 32 m-rows, all 64 n-cols
  __shared__ short Bl[64 * 512];      // 64 KB, row-swizzled
  __shared__ float scr[4][16][64];    // 16 KB epilogue staging (per-wave region)

  // stage B once: w_fc rows n0..n0+63, full K
#pragma unroll
  for (int j = 0; j < 16; ++j) {
    int idx = j * 256 + tid;        // 0..4095 chunks of 8 shorts
    int row = idx >> 6, c8 = idx & 63;
    int sw = (c8 * 16) ^ ((row & 7) << 4);
    short8 vb = *(const short8*)(w_fc + (size_t)(n0 + row) * 512 + c8 * 8);
    *(short8*)((char*)Bl + row * 1024 + sw) = vb;
  }
  __syncthreads();

  float bias[4];
  int lenr[2][4];
#pragma unroll
  for (int nf = 0; nf < 4; ++nf) bias[nf] = ldw(fl, b_fc, n0 + nf * 16 + rlo);
#pragma unroll
  for (int mt = 0; mt < 2; ++mt)
#pragma unroll
    for (int r = 0; r < 4; ++r) lenr[mt][r] = lengths[mw + mt * 16 + quad * 4 + r];

  for (int t = 0; t < NT; ++t) {
    // batch-preload A for this t: k-major layout -> 4x256B segments per load instr
    const short* abase = hnall + (size_t)t * 65536 + quad * 1024;
    short8 areg[2][16];
#pragma unroll
    for (int mt = 0; mt < 2; ++mt)
#pragma unroll
      for (int ks = 0; ks < 16; ++ks)
        areg[mt][ks] = *(const short8*)(abase + ks * 4096 + (mw + mt * 16 + rlo) * 8);

    floatx4 acc[2][4];
#pragma unroll
    for (int mt = 0; mt < 2; ++mt)
#pragma unroll
      for (int nf = 0; nf < 4; ++nf) acc[mt][nf] = (floatx4){0.f, 0.f, 0.f, 0.f};

#pragma unroll
    for (int ks = 0; ks < 16; ++ks) {
      short8 bfr[4];
#pragma unroll
      for (int nf = 0; nf < 4; ++nf) {
        int row = nf * 16 + rlo;
        bfr[nf] = *(const short8*)((const char*)Bl + row * 1024 +
                                   ((ks * 64 + quad * 16) ^ ((row & 7) << 4)));
      }
#pragma unroll
      for (int mt = 0; mt < 2; ++mt)
#pragma unroll
        for (int nf = 0; nf < 4; ++nf)
          acc[mt][nf] = __builtin_amdgcn_mfma_f32_16x16x32_bf16(areg[mt][ks], bfr[nf], acc[mt][nf], 0, 0, 0);
    }

    // epilogue: stage through LDS, then full-line nontemporal stores
#pragma unroll
    for (int mt = 0; mt < 2; ++mt) {
#pragma unroll
      for (int nf = 0; nf < 4; ++nf)
#pragma unroll
        for (int r = 0; r < 4; ++r) {
          bool act = t < lenr[mt][r] - 1;
          scr[wave][quad * 4 + r][nf * 16 + rlo] = act ? (acc[mt][nf][r] + bias[nf]) : 0.f;
        }
      __syncthreads();
#pragma unroll
      for (int g = 0; g < 4; ++g) {
        int rowl = g * 4 + (lane >> 4);       // 0..15
        int col = (lane & 15) * 4;            // 0..60
        floatx4 v = *(const floatx4*)&scr[wave][rowl][col];
        int bb = mw + mt * 16 + rowl;
        size_t oi = ((size_t)bb * NT + t) * NV + n0 + col;
        if (fl) {
          short4v o;
          o[0] = f2bf(v[0]); o[1] = f2bf(v[1]); o[2] = f2bf(v[2]); o[3] = f2bf(v[3]);
          __builtin_nontemporal_store(o, (short4v*)&((short*)d_out)[oi]);
        } else {
          __builtin_nontemporal_store(v, (floatx4*)&((float*)d_out)[oi]);
        }
      }
      __syncthreads();
    }
  }
}

extern "C" void kernel_launch(void* const* d_in, const int* in_sizes, int n_in,
                              void* d_out, int out_size, void* d_ws, size_t ws_size,
                              hipStream_t stream) {
  const void* features = d_in[0];
  const int* captions = (const int*)d_in[1];
  const int* lengths = (const int*)d_in[2];
  const void* w_enc_att = d_in[3];
  const void* b_enc_att = d_in[4];
  const void* w_dec_att = d_in[5];
  const void* b_dec_att = d_in[6];
  const void* w_full = d_in[7];
  const void* embed_w = d_in[9];
  const void* w_ih = d_in[10];
  const void* b_ih = d_in[11];
  const void* w_hh = d_in[12];
  const void* b_hh = d_in[13];
  const void* w_init_h = d_in[14];
  const void* b_init_h = d_in[15];
  const void* w_init_c = d_in[16];
  const void* b_init_c = d_in[17];
  const void* w_beta = d_in[18];
  const void* b_beta = d_in[19];
  const void* w_fc = d_in[20];
  const void* b_fc = d_in[21];

  char* ws = (char*)d_ws;
  int* flagp = (int*)ws; ws += 16;
  short* cfeat = (short*)ws; ws += (size_t)12845056 * 2;
  short* cembed = (short*)ws; ws += (size_t)16384000 * 2;
  short* cwfc = (short*)ws; ws += (size_t)16384000 * 2;
  short* cwih = (short*)ws; ws += (size_t)2097152 * 2;
  short* cwhh = (short*)ws; ws += (size_t)1048576 * 2;
  short* cwenc = (short*)ws; ws += (size_t)262144 * 2;
  short* cwdec = (short*)ws; ws += (size_t)262144 * 2;
  short* cwbeta = (short*)ws; ws += (size_t)262144 * 2;
  short* cwinith = (short*)ws; ws += (size_t)262144 * 2;
  short* cwinitc = (short*)ws; ws += (size_t)262144 * 2;
  short* att1 = (short*)ws; ws += (size_t)25088 * 512 * 2;
  float* xp   = (float*)ws; ws += (size_t)2432 * 2048 * 4;
  float* abuf = (float*)ws; ws += (size_t)128 * 3072 * 4;
  float* escore = (float*)ws; ws += (size_t)25088 * 4;
  short* hbuf = (short*)ws; ws += 128 * 512 * 2;
  short* hnall = (short*)ws; ws += (size_t)NT * 128 * 512 * 2;
  short* awe  = (short*)ws; ws += 128 * 512 * 2;
  short* fmean = (short*)ws; ws += 128 * 512 * 2;
  float* cbuf = (float*)ws; ws += 128 * 512 * 4;

  k_detect<<<1, 256, 0, stream>>>((const unsigned int*)features, flagp);
  k_convall<<<2048, 256, 0, stream>>>(features, embed_w, w_fc, w_ih, w_hh,
                                      w_enc_att, w_dec_att, w_beta, w_init_h, w_init_c,
                                      cfeat, flagp);

  k_fmean<<<128, 256, 0, stream>>>(cfeat, fmean);
  k_att1<<<dim3(8, 196), 256, 0, stream>>>(cfeat, cwenc, b_enc_att, att1, flagp);
  k_xpart<<<dim3(32, NT), 256, 0, stream>>>(captions, cembed, cwih, b_ih, b_hh, xp, flagp);
  k_init<<<16, 256, 0, stream>>>(fmean, cwinith, b_init_h, cwinitc, b_init_c, hbuf, cbuf, flagp);

  for (int t = 0; t < NT; ++t) {
    k_hproj<<<48, 256, 0, stream>>>(hbuf, cwdec, b_dec_att, cwbeta, b_beta, cwhh, abuf, flagp);
    k_score<<<784, 256, 0, stream>>>(att1, abuf, w_full, escore, flagp);
    k_ctx<<<dim3(4, 128), 256, 0, stream>>>(escore, cfeat, abuf, lengths, awe, d_out, flagp, t);
    k_gates_lstm<<<32, 256, 0, stream>>>(awe, cwih, xp, abuf, lengths, cbuf, hbuf, hnall, t);
  }
  k_preds_all<<<500, 256, 0, stream>>>(hnall, cwfc, b_fc, lengths, d_out, flagp);
}